// Round 21
// baseline (111.711 us; speedup 1.0000x reference)
//
#include <hip/hip_runtime.h>
#include <math.h>

#define KDIM 100
#define DDIM 64

typedef __bf16 bf16x8 __attribute__((ext_vector_type(8)));
typedef float  f32x4  __attribute__((ext_vector_type(4)));
typedef float  f32x2  __attribute__((ext_vector_type(2)));
typedef unsigned int u32;
typedef u32 u32x2 __attribute__((ext_vector_type(2)));

struct Weights {
  const float *w1, *b1, *w2, *b2, *w3, *b3, *w4, *b4, *w5, *b5;
};

__device__ __forceinline__ f32x2 vmax2(f32x2 a, f32x2 b) {
#if __has_builtin(__builtin_elementwise_max)
  return __builtin_elementwise_max(a, b);
#else
  return (f32x2){fmaxf(a[0], b[0]), fmaxf(a[1], b[1])};
#endif
}

// ---------------- mlp LDS layout ----------------
// floats: L_VEC [4][100] | L_PA [4][128] | L_TAIL [512] | L_C [2][128]
constexpr int L_VEC  = 0;
constexpr int L_PA   = 400;
constexpr int L_TAIL = 912;   // b1[2][128]@0 b2[2][64]@256 b3[2][32]@384 b4[2][16]@448 w5[2][16]@480
constexpr int L_C    = 1424;
constexpr int SM_F   = 1680;                     // 6720 B
constexpr int H2T_BYTE = SM_F * 4;               // 6720; 8 waves x 16 rows x 128 B (swizzled)
constexpr int H3T_BYTE = H2T_BYTE + 8 * 2048;    // 23104; 8 waves x 16 rows x 64 B (swizzled)
constexpr int SM_BYTES = H3T_BYTE + 8 * 1024;    // 31296 B

// ---------------- kernel 1: rowsums + transposed A-frag pack + bias tail ----------------
// wfrag: [net(2)][frag f(21)][lane(64)][8 bf16].
// f 0-15:  W2^T A-frag (mt=f>>2, ks=f&3): elem i = w2[32ks+8g+i][16mt+c16]
// f 16-19: W3^T (mt=(f-16)>>1, ks=(f-16)&1): elem i = w3[32ks+8g+i][16mt+c16]
// f 20:    W4^T: elem i = w4[8g+i][c16]
__global__ void prep_kernel(const float* __restrict__ user_emb,
                            const float* __restrict__ item_emb,
                            float* __restrict__ u_rowsum,
                            float* __restrict__ i_rowsum,
                            int NU, int NI, Weights N1, Weights N2,
                            __bf16* __restrict__ wfrag, float* __restrict__ tail) {
  const int tid  = threadIdx.x;
  const int lane = tid & 63;
  const int g = lane >> 4, c16 = lane & 15;
  const int gw = (blockIdx.x * blockDim.x + tid) >> 6;

  if (gw < 42) {
    const int net = gw / 21, f = gw % 21;
    const Weights W = net ? N2 : N1;
    bf16x8 v;
    if (f < 16) {
      const int mt = f >> 2, ks = f & 3;
      #pragma unroll
      for (int i = 0; i < 8; ++i) {
        const int k = 32 * ks + 8 * g + i, m = 16 * mt + c16;
        v[i] = (__bf16)((k < 100 && m < 50) ? W.w2[k * 50 + m] : 0.f);
      }
    } else if (f < 20) {
      const int mt = (f - 16) >> 1, ks = (f - 16) & 1;
      #pragma unroll
      for (int i = 0; i < 8; ++i) {
        const int k = 32 * ks + 8 * g + i, m = 16 * mt + c16;
        v[i] = (__bf16)((k < 50 && m < 25) ? W.w3[k * 25 + m] : 0.f);
      }
    } else {
      #pragma unroll
      for (int i = 0; i < 8; ++i) {
        const int k = 8 * g + i, m = c16;
        v[i] = (__bf16)((k < 25 && m < 12) ? W.w4[k * 12 + m] : 0.f);
      }
    }
    *(bf16x8*)(wfrag + (size_t)gw * 512 + lane * 8) = v;
  }

  if (blockIdx.x == 0) {
    for (int e = tid; e < 512; e += 256) {
      float v;
      if (e < 256)      { const int j = e & 127; const Weights W = (e & 128) ? N2 : N1; v = (j < 100) ? W.b1[j] : 0.f; }
      else if (e < 384) { const int t = e - 256; const int j = t & 63; const Weights W = (t & 64) ? N2 : N1; v = (j < 50) ? W.b2[j] : 0.f; }
      else if (e < 448) { const int t = e - 384; const int j = t & 31; const Weights W = (t & 32) ? N2 : N1; v = (j < 25) ? W.b3[j] : 0.f; }
      else if (e < 480) { const int t = e - 448; const int j = t & 15; const Weights W = (t & 16) ? N2 : N1; v = (j < 12) ? W.b4[j] : 0.f; }
      else              { const int t = e - 480; const int j = t & 15; const Weights W = (t & 16) ? N2 : N1; v = (j < 12) ? W.w5[j] : 0.f; }
      tail[e] = v;
    }
  }

  const int NR = NU + NI;
  const int chunk = lane & 15, lrow = lane >> 4;
  const int nwave = (gridDim.x * blockDim.x) >> 6;
  for (int base = gw * 4; base < NR; base += nwave * 4) {
    const int r = base + lrow;
    float s = 0.f;
    if (r < NR) {
      const float* src = (r < NU) ? (user_emb + (size_t)r * DDIM)
                                  : (item_emb + (size_t)(r - NU) * DDIM);
      const float4 v4 = ((const float4*)src)[chunk];
      s = v4.x + v4.y + v4.z + v4.w;
    }
    s += __shfl_xor(s, 1); s += __shfl_xor(s, 2);
    s += __shfl_xor(s, 4); s += __shfl_xor(s, 8);
    if (chunk == 0 && r < NR) {
      if (r < NU) u_rowsum[r] = s; else i_rowsum[r - NU] = s;
    }
  }
}

// ---------------- kernel 2: batched layer-1 projections (TILE_B = 16) ----------------
__global__ void __launch_bounds__(256) proj_kernel(
    const int* __restrict__ user_idxs, const int* __restrict__ item_idxs,
    const int* __restrict__ uidx_t, const int* __restrict__ iidx_t,
    const float* __restrict__ uscr, const float* __restrict__ iscr,
    const float* __restrict__ u_rowsum, const float* __restrict__ i_rowsum,
    const float* __restrict__ n1w1, const float* __restrict__ n2w1,
    float* __restrict__ VG, float* __restrict__ PAG, int B)
{
  __shared__ float VT[100][20];
  __shared__ float W1S[50][128];
  __shared__ int sidx[16];
  const int tid = threadIdx.x;
  const int sel = blockIdx.x & 3;
  const int b0  = (blockIdx.x >> 2) * 16;

  if (tid < 16) {
    const int b = b0 + tid;
    const int bb = (b < B) ? b : (B - 1);
    sidx[tid] = (sel & 1) ? item_idxs[bb] : user_idxs[bb];
  }
  __syncthreads();

  {
    const int bl = tid >> 4, strip = tid & 15;
    const size_t row = (size_t)sidx[bl] * KDIM;
    if (sel < 2) {
      const int* it = (sel == 0) ? uidx_t : iidx_t;
      const float* rs = (sel == 0) ? u_rowsum : i_rowsum;
      int idxs[7];
      #pragma unroll
      for (int i = 0; i < 7; ++i) {
        const int k = strip + 16 * i;
        idxs[i] = (k < KDIM) ? it[row + k] : 0;
      }
      #pragma unroll
      for (int i = 0; i < 7; ++i) {
        const int k = strip + 16 * i;
        if (k < KDIM) VT[k][bl] = rs[idxs[i]];
      }
    } else {
      const float* sc = (sel == 2) ? uscr : iscr;
      #pragma unroll
      for (int i = 0; i < 7; ++i) {
        const int k = strip + 16 * i;
        if (k < KDIM) VT[k][bl] = sc[row + k];
      }
    }
  }

  const float* w1 = (sel < 2) ? n1w1 : n2w1;
  const int rb = (sel & 1) * KDIM;
  const int jg = tid & 31, bg = tid >> 5;
  float acc[2][4];
  #pragma unroll
  for (int bi = 0; bi < 2; ++bi)
    #pragma unroll
    for (int ji = 0; ji < 4; ++ji) acc[bi][ji] = 0.f;

  for (int kh = 0; kh < 2; ++kh) {
    __syncthreads();
    for (int e = tid; e < 1600; e += 256) {
      const int k = e >> 5, s = e & 31;
      float4 v;
      if (s < 25) v = ((const float4*)(w1 + (size_t)(rb + kh * 50 + k) * KDIM))[s];
      else        v = make_float4(0.f, 0.f, 0.f, 0.f);
      *(float4*)&W1S[k][4 * s] = v;
    }
    __syncthreads();
    #pragma unroll 2
    for (int k = 0; k < 50; ++k) {
      const f32x2 v = *(const f32x2*)&VT[kh * 50 + k][2 * bg];
      const float4 w = *(const float4*)&W1S[k][4 * jg];
      const float ww[4] = {w.x, w.y, w.z, w.w};
      #pragma unroll
      for (int ji = 0; ji < 4; ++ji) {
        acc[0][ji] = fmaf(v[0], ww[ji], acc[0][ji]);
        acc[1][ji] = fmaf(v[1], ww[ji], acc[1][ji]);
      }
    }
  }

  #pragma unroll
  for (int bi = 0; bi < 2; ++bi) {
    const int b = b0 + 2 * bg + bi;
    if (b < B) {
      float4 o = make_float4(acc[bi][0], acc[bi][1], acc[bi][2], acc[bi][3]);
      *(float4*)(PAG + ((size_t)sel * B + b) * 128 + 4 * jg) = o;
    }
  }
  {
    const int bl = tid >> 4, strip = tid & 15;
    const int b = b0 + bl;
    if (b < B) {
      float* dst = VG + ((size_t)sel * B + b) * KDIM;
      #pragma unroll
      for (int i = 0; i < 7; ++i) {
        const int k = strip + 16 * i;
        if (k < KDIM) dst[k] = VT[k][bl];
      }
    }
  }
}

// ---------------- kernel 3: register-preloaded swapped-operand MFMA chain ----------------
// 512 threads = 8 waves; wave wv: net = wv>>2, quarter q = wv&3 (rows 25q..25q+24).
// NEW vs R15: ALL 21 weight A-frags preloaded into registers BEFORE the phase-0
// barrier (their ~300cy L2 latency hides under the staging barrier); the MFMA chain
// then reads only registers + small LDS tails. launch_bounds(512,1) -> VGPR cap 256
// (2nd arg = min BLOCKS/CU on this toolchain; see R14/R19 spill post-mortems).
__global__ void __launch_bounds__(512, 1) mlp_kernel(
    const float* __restrict__ VG, const float* __restrict__ PAG,
    const float* __restrict__ tail,
    const float* __restrict__ n1b5, const float* __restrict__ n2b5,
    const __bf16* __restrict__ wfrag, float* __restrict__ out, int B)
{
  __shared__ __align__(16) char smem[SM_BYTES];
  float* sm = (float*)smem;
  const int tid  = threadIdx.x;
  const int lane = tid & 63;
  const int wv   = tid >> 6;
  const int g    = lane >> 4;
  const int c16  = lane & 15;
  const int b    = blockIdx.x;
  const f32x2 Z2 = {0.f, 0.f};

  const int net = wv >> 2;
  const char* wfb = (const char*)wfrag + net * 21 * 1024;

  // ---- preload ALL weight frags to registers (latency hidden under phase-0 barrier)
  bf16x8 wf2[16], wf3[4], wf4;
  #pragma unroll
  for (int f = 0; f < 16; ++f) wf2[f] = *(const bf16x8*)(wfb + f * 1024 + lane * 16);
  #pragma unroll
  for (int f = 0; f < 4; ++f)  wf3[f] = *(const bf16x8*)(wfb + (16 + f) * 1024 + lane * 16);
  wf4 = *(const bf16x8*)(wfb + 20 * 1024 + lane * 16);

  // ---- phase 0: stage PA + tail + V (small, coalesced)
  if (tid < 128) {
    const int sel = tid >> 5, s = tid & 31;
    *(float4*)&sm[L_PA + sel * 128 + 4 * s] =
        *(const float4*)(PAG + ((size_t)sel * B + b) * 128 + 4 * s);
  } else if (tid < 256) {
    const int t = tid - 128;
    *(float4*)&sm[L_TAIL + 4 * t] = *(const float4*)(tail + 4 * t);
  } else if (tid < 456) {
    const int e = tid - 256;
    const int sel = e / 50, r = e % 50;
    *(f32x2*)&sm[L_VEC + sel * 100 + 2 * r] =
        *(const f32x2*)(VG + ((size_t)sel * B + b) * KDIM + 2 * r);
  }
  __syncthreads();

  const int q   = wv & 3;
  const int r0  = 25 * q;
  const int vA  = net ? (L_VEC + 0)   : (L_VEC + 200);  // net1: sums, net0: scores
  const int vB  = net ? (L_VEC + 100) : (L_VEC + 300);
  const int pAo = L_PA + net * 256;
  const int pBo = pAo + 128;
  char* h2t = smem + H2T_BYTE + wv * 2048;  // [16 rows][128 B], swizzled
  char* h3t = smem + H3T_BYTE + wv * 1024;  // [16 rows][64 B], swizzled
  const float b5v = net ? n2b5[0] : n1b5[0];
  const int t7 = c16 & 7, t3 = c16 & 3;

  float sAr[2], sBr[2];
  #pragma unroll
  for (int c = 0; c < 2; ++c) {
    const int row = r0 + 16 * c + c16;
    const int rr = row < KDIM ? row : (KDIM - 1);   // clamp; pad rows filtered at write
    sAr[c] = sm[vA + rr]; sBr[c] = sm[vB + rr];
  }

  // ---- layer 2: acc2[chunk][mt] += mfma(W2T[mt][ks], h1frag[chunk][ks])
  f32x4 acc2[2][4];
  #pragma unroll
  for (int c = 0; c < 2; ++c)
    #pragma unroll
    for (int mt = 0; mt < 4; ++mt) acc2[c][mt] = (f32x4){0.f, 0.f, 0.f, 0.f};

  #pragma unroll
  for (int ks = 0; ks < 4; ++ks) {
    const int jb = 32 * ks + 8 * g;
    const f32x2* pa2 = (const f32x2*)&sm[pAo + jb];
    const f32x2* pb2 = (const f32x2*)&sm[pBo + jb];
    const f32x2* b12 = (const f32x2*)&sm[L_TAIL + net * 128 + jb];
    f32x2 paf[4], pbf[4], b1f[4];
    #pragma unroll
    for (int i = 0; i < 4; ++i) { paf[i] = pa2[i]; pbf[i] = pb2[i]; b1f[i] = b12[i]; }
    bf16x8 hb[2];
    #pragma unroll
    for (int c = 0; c < 2; ++c) {
      const f32x2 sa = {sAr[c], sAr[c]}, sb = {sBr[c], sBr[c]};
      bf16x8 a;
      #pragma unroll
      for (int i2 = 0; i2 < 4; ++i2) {
        f32x2 t = sb * pbf[i2] + b1f[i2];   // v_pk_fma_f32 (contracted)
        t = sa * paf[i2] + t;               // v_pk_fma_f32
        t = vmax2(t, Z2);
        a[2 * i2]     = (__bf16)t[0];       // paired -> v_cvt_pk_bf16_f32
        a[2 * i2 + 1] = (__bf16)t[1];
      }
      hb[c] = a;
    }
    __builtin_amdgcn_s_setprio(1);
    #pragma unroll
    for (int mt = 0; mt < 4; ++mt) {
      acc2[0][mt] = __builtin_amdgcn_mfma_f32_16x16x32_bf16(wf2[mt * 4 + ks], hb[0], acc2[0][mt], 0, 0, 0);
      acc2[1][mt] = __builtin_amdgcn_mfma_f32_16x16x32_bf16(wf2[mt * 4 + ks], hb[1], acc2[1][mt], 0, 0, 0);
    }
    __builtin_amdgcn_s_setprio(0);
  }

  // ---- per-chunk: h2 epilogue -> L3 -> h3 epilogue -> L4+L5
  #pragma unroll
  for (int c = 0; c < 2; ++c) {
    #pragma unroll
    for (int mt = 0; mt < 4; ++mt) {
      const f32x2* b2p = (const f32x2*)&sm[L_TAIL + 256 + net * 64 + 16 * mt + 4 * g];
      const f32x4 x = acc2[c][mt];
      const f32x2 lo = vmax2((f32x2){x[0], x[1]} + b2p[0], Z2);
      const f32x2 hi = vmax2((f32x2){x[2], x[3]} + b2p[1], Z2);
      union { __bf16 e[4]; u32x2 w; } o;
      o.e[0] = (__bf16)lo[0]; o.e[1] = (__bf16)lo[1];
      o.e[2] = (__bf16)hi[0]; o.e[3] = (__bf16)hi[1];
      const int S = (2 * mt + (g >> 1)) ^ t7;
      *(u32x2*)(h2t + c16 * 128 + S * 16 + (g & 1) * 8) = o.w;
    }

    // layer 3: h3^T = W3^T @ h2^T
    f32x4 acc3[2];
    #pragma unroll
    for (int mt = 0; mt < 2; ++mt) acc3[mt] = (f32x4){0.f, 0.f, 0.f, 0.f};
    #pragma unroll
    for (int ks = 0; ks < 2; ++ks) {
      const int S = (4 * ks + g) ^ t7;
      const bf16x8 hbf = *(const bf16x8*)(h2t + c16 * 128 + S * 16);
      __builtin_amdgcn_s_setprio(1);
      #pragma unroll
      for (int mt = 0; mt < 2; ++mt)
        acc3[mt] = __builtin_amdgcn_mfma_f32_16x16x32_bf16(wf3[mt * 2 + ks], hbf, acc3[mt], 0, 0, 0);
      __builtin_amdgcn_s_setprio(0);
    }
    #pragma unroll
    for (int mt = 0; mt < 2; ++mt) {
      const f32x2* b3p = (const f32x2*)&sm[L_TAIL + 384 + net * 32 + 16 * mt + 4 * g];
      const f32x4 x = acc3[mt];
      const f32x2 lo = vmax2((f32x2){x[0], x[1]} + b3p[0], Z2);
      const f32x2 hi = vmax2((f32x2){x[2], x[3]} + b3p[1], Z2);
      union { __bf16 e[4]; u32x2 w; } o;
      o.e[0] = (__bf16)lo[0]; o.e[1] = (__bf16)lo[1];
      o.e[2] = (__bf16)hi[0]; o.e[3] = (__bf16)hi[1];
      const int S = (2 * mt + (g >> 1)) ^ t3;
      *(u32x2*)(h3t + c16 * 64 + S * 16 + (g & 1) * 8) = o.w;
    }

    // layer 4 + 5 + per-row reduce
    {
      const int S = g ^ t3;
      const bf16x8 hbf = *(const bf16x8*)(h3t + c16 * 64 + S * 16);
      const f32x4 z = {0.f, 0.f, 0.f, 0.f};
      __builtin_amdgcn_s_setprio(1);
      const f32x4 acc4 = __builtin_amdgcn_mfma_f32_16x16x32_bf16(wf4, hbf, z, 0, 0, 0);
      __builtin_amdgcn_s_setprio(0);
      const f32x2* b4p = (const f32x2*)&sm[L_TAIL + 448 + net * 16 + 4 * g];
      const f32x2* w5p = (const f32x2*)&sm[L_TAIL + 480 + net * 16 + 4 * g];
      const f32x2 lo = vmax2((f32x2){acc4[0], acc4[1]} + b4p[0], Z2);
      const f32x2 hi = vmax2((f32x2){acc4[2], acc4[3]} + b4p[1], Z2);
      float v = lo[0] * w5p[0][0] + lo[1] * w5p[0][1]
              + hi[0] * w5p[1][0] + hi[1] * w5p[1][1];   // pad cols: b4=w5=0
      v += __shfl_xor(v, 16); v += __shfl_xor(v, 32);
      const int lr = 16 * c + c16;
      if (g == 0 && lr < 25)
        sm[L_C + net * 128 + r0 + lr] = v + b5v;
    }
  }
  __syncthreads();

  // ---- final: sum rows 0..99 of both nets -> sigmoid(mean)
  float v = 0.f;
  if (tid < KDIM) v = sm[L_C + tid] + sm[L_C + 128 + tid];
  if (tid < 128) {
    #pragma unroll
    for (int d = 1; d < 64; d <<= 1) v += __shfl_xor(v, d);
    if ((tid & 63) == 0) sm[tid >> 6] = v;
  }
  __syncthreads();
  if (tid == 0) out[b] = 1.f / (1.f + expf(-0.01f * (sm[0] + sm[1])));
}

extern "C" void kernel_launch(void* const* d_in, const int* in_sizes, int n_in,
                              void* d_out, int out_size, void* d_ws, size_t ws_size,
                              hipStream_t stream) {
  const int*   user_idxs = (const int*)d_in[0];
  const int*   item_idxs = (const int*)d_in[1];
  const int*   uidx_t    = (const int*)d_in[2];
  const int*   iidx_t    = (const int*)d_in[3];
  const float* uscr      = (const float*)d_in[4];
  const float* iscr      = (const float*)d_in[5];
  const float* uemb      = (const float*)d_in[6];
  const float* iemb      = (const float*)d_in[7];

  const int B  = in_sizes[0];
  const int NU = in_sizes[6] / DDIM;
  const int NI = in_sizes[7] / DDIM;

  Weights N1 { (const float*)d_in[8],  (const float*)d_in[9],
               (const float*)d_in[10], (const float*)d_in[11],
               (const float*)d_in[12], (const float*)d_in[13],
               (const float*)d_in[14], (const float*)d_in[15],
               (const float*)d_in[16], (const float*)d_in[17] };
  Weights N2 { (const float*)d_in[18], (const float*)d_in[19],
               (const float*)d_in[20], (const float*)d_in[21],
               (const float*)d_in[22], (const float*)d_in[23],
               (const float*)d_in[24], (const float*)d_in[25],
               (const float*)d_in[26], (const float*)d_in[27] };

  char* ws = (char*)d_ws;
  float* u_rowsum = (float*)ws;
  float* i_rowsum = u_rowsum + NU;
  size_t off = (((size_t)(NU + NI) * 4 + 1023) & ~(size_t)1023);
  __bf16* wfrag = (__bf16*)(ws + off);                 // 42*512 bf16 = 43008 B
  float*  tail  = (float*)(wfrag + (size_t)42 * 512);  // 512 f32
  off += (((size_t)42 * 512 * 2 + 512 * 4 + 1023) & ~(size_t)1023);
  float* VG  = (float*)(ws + off);                     // [4][B][100]
  off += (size_t)4 * B * KDIM * 4;
  float* PAG = (float*)(ws + off);                     // [4][B][128]

  float* out = (float*)d_out;

  prep_kernel<<<1024, 256, 0, stream>>>(uemb, iemb, u_rowsum, i_rowsum, NU, NI, N1, N2, wfrag, tail);
  const int nbt = (B + 15) / 16;
  proj_kernel<<<nbt * 4, 256, 0, stream>>>(user_idxs, item_idxs, uidx_t, iidx_t,
                                           uscr, iscr, u_rowsum, i_rowsum,
                                           N1.w1, N2.w1, VG, PAG, B);
  mlp_kernel<<<B, 512, 0, stream>>>(VG, PAG, tail, N1.b5, N2.b5, wfrag, out, B);
}

// Round 22
// 76.837 us; speedup vs baseline: 1.4539x; 1.4539x over previous
//
#include <hip/hip_runtime.h>
#include <math.h>

#define KDIM 100
#define DDIM 64

typedef __bf16 bf16x8 __attribute__((ext_vector_type(8)));
typedef float  f32x4  __attribute__((ext_vector_type(4)));
typedef float  f32x2  __attribute__((ext_vector_type(2)));
typedef unsigned int u32;
typedef u32 u32x2 __attribute__((ext_vector_type(2)));

struct Weights {
  const float *w1, *b1, *w2, *b2, *w3, *b3, *w4, *b4, *w5, *b5;
};

__device__ __forceinline__ f32x2 vmax2(f32x2 a, f32x2 b) {
#if __has_builtin(__builtin_elementwise_max)
  return __builtin_elementwise_max(a, b);
#else
  return (f32x2){fmaxf(a[0], b[0]), fmaxf(a[1], b[1])};
#endif
}

// ---------------- mlp LDS layout (256-thread blocks, 4 waves) ----------------
// floats: L_VEC [4][100] | L_PA [4][128] | L_TAIL [512] | L_C [2][128]
constexpr int L_VEC  = 0;
constexpr int L_PA   = 400;
constexpr int L_TAIL = 912;   // b1[2][128]@0 b2[2][64]@256 b3[2][32]@384 b4[2][16]@448 w5[2][16]@480
constexpr int L_C    = 1424;
constexpr int SM_F   = 1680;                     // 6720 B
constexpr int H2T_BYTE = SM_F * 4;               // 6720; 4 waves x 16 rows x 128 B (swizzled)
constexpr int H3T_BYTE = H2T_BYTE + 4 * 2048;    // 14912; 4 waves x 16 rows x 64 B (swizzled)
constexpr int SM_BYTES = H3T_BYTE + 4 * 1024;    // 19008 B -> 8 blocks/CU by LDS

// ---------------- kernel 1: rowsums + transposed A-frag pack + bias tail ----------------
// wfrag: [net(2)][frag f(21)][lane(64)][8 bf16].
// f 0-15:  W2^T A-frag (mt=f>>2, ks=f&3): elem i = w2[32ks+8g+i][16mt+c16]
// f 16-19: W3^T (mt=(f-16)>>1, ks=(f-16)&1): elem i = w3[32ks+8g+i][16mt+c16]
// f 20:    W4^T: elem i = w4[8g+i][c16]
__global__ void prep_kernel(const float* __restrict__ user_emb,
                            const float* __restrict__ item_emb,
                            float* __restrict__ u_rowsum,
                            float* __restrict__ i_rowsum,
                            int NU, int NI, Weights N1, Weights N2,
                            __bf16* __restrict__ wfrag, float* __restrict__ tail) {
  const int tid  = threadIdx.x;
  const int lane = tid & 63;
  const int g = lane >> 4, c16 = lane & 15;
  const int gw = (blockIdx.x * blockDim.x + tid) >> 6;

  if (gw < 42) {
    const int net = gw / 21, f = gw % 21;
    const Weights W = net ? N2 : N1;
    bf16x8 v;
    if (f < 16) {
      const int mt = f >> 2, ks = f & 3;
      #pragma unroll
      for (int i = 0; i < 8; ++i) {
        const int k = 32 * ks + 8 * g + i, m = 16 * mt + c16;
        v[i] = (__bf16)((k < 100 && m < 50) ? W.w2[k * 50 + m] : 0.f);
      }
    } else if (f < 20) {
      const int mt = (f - 16) >> 1, ks = (f - 16) & 1;
      #pragma unroll
      for (int i = 0; i < 8; ++i) {
        const int k = 32 * ks + 8 * g + i, m = 16 * mt + c16;
        v[i] = (__bf16)((k < 50 && m < 25) ? W.w3[k * 25 + m] : 0.f);
      }
    } else {
      #pragma unroll
      for (int i = 0; i < 8; ++i) {
        const int k = 8 * g + i, m = c16;
        v[i] = (__bf16)((k < 25 && m < 12) ? W.w4[k * 12 + m] : 0.f);
      }
    }
    *(bf16x8*)(wfrag + (size_t)gw * 512 + lane * 8) = v;
  }

  if (blockIdx.x == 0) {
    for (int e = tid; e < 512; e += 256) {
      float v;
      if (e < 256)      { const int j = e & 127; const Weights W = (e & 128) ? N2 : N1; v = (j < 100) ? W.b1[j] : 0.f; }
      else if (e < 384) { const int t = e - 256; const int j = t & 63; const Weights W = (t & 64) ? N2 : N1; v = (j < 50) ? W.b2[j] : 0.f; }
      else if (e < 448) { const int t = e - 384; const int j = t & 31; const Weights W = (t & 32) ? N2 : N1; v = (j < 25) ? W.b3[j] : 0.f; }
      else if (e < 480) { const int t = e - 448; const int j = t & 15; const Weights W = (t & 16) ? N2 : N1; v = (j < 12) ? W.b4[j] : 0.f; }
      else              { const int t = e - 480; const int j = t & 15; const Weights W = (t & 16) ? N2 : N1; v = (j < 12) ? W.w5[j] : 0.f; }
      tail[e] = v;
    }
  }

  const int NR = NU + NI;
  const int chunk = lane & 15, lrow = lane >> 4;
  const int nwave = (gridDim.x * blockDim.x) >> 6;
  for (int base = gw * 4; base < NR; base += nwave * 4) {
    const int r = base + lrow;
    float s = 0.f;
    if (r < NR) {
      const float* src = (r < NU) ? (user_emb + (size_t)r * DDIM)
                                  : (item_emb + (size_t)(r - NU) * DDIM);
      const float4 v4 = ((const float4*)src)[chunk];
      s = v4.x + v4.y + v4.z + v4.w;
    }
    s += __shfl_xor(s, 1); s += __shfl_xor(s, 2);
    s += __shfl_xor(s, 4); s += __shfl_xor(s, 8);
    if (chunk == 0 && r < NR) {
      if (r < NU) u_rowsum[r] = s; else i_rowsum[r - NU] = s;
    }
  }
}

// ---------------- kernel 2: batched layer-1 projections (TILE_B = 16) ----------------
__global__ void __launch_bounds__(256) proj_kernel(
    const int* __restrict__ user_idxs, const int* __restrict__ item_idxs,
    const int* __restrict__ uidx_t, const int* __restrict__ iidx_t,
    const float* __restrict__ uscr, const float* __restrict__ iscr,
    const float* __restrict__ u_rowsum, const float* __restrict__ i_rowsum,
    const float* __restrict__ n1w1, const float* __restrict__ n2w1,
    float* __restrict__ VG, float* __restrict__ PAG, int B)
{
  __shared__ float VT[100][20];
  __shared__ float W1S[50][128];
  __shared__ int sidx[16];
  const int tid = threadIdx.x;
  const int sel = blockIdx.x & 3;
  const int b0  = (blockIdx.x >> 2) * 16;

  if (tid < 16) {
    const int b = b0 + tid;
    const int bb = (b < B) ? b : (B - 1);
    sidx[tid] = (sel & 1) ? item_idxs[bb] : user_idxs[bb];
  }
  __syncthreads();

  {
    const int bl = tid >> 4, strip = tid & 15;
    const size_t row = (size_t)sidx[bl] * KDIM;
    if (sel < 2) {
      const int* it = (sel == 0) ? uidx_t : iidx_t;
      const float* rs = (sel == 0) ? u_rowsum : i_rowsum;
      int idxs[7];
      #pragma unroll
      for (int i = 0; i < 7; ++i) {
        const int k = strip + 16 * i;
        idxs[i] = (k < KDIM) ? it[row + k] : 0;
      }
      #pragma unroll
      for (int i = 0; i < 7; ++i) {
        const int k = strip + 16 * i;
        if (k < KDIM) VT[k][bl] = rs[idxs[i]];
      }
    } else {
      const float* sc = (sel == 2) ? uscr : iscr;
      #pragma unroll
      for (int i = 0; i < 7; ++i) {
        const int k = strip + 16 * i;
        if (k < KDIM) VT[k][bl] = sc[row + k];
      }
    }
  }

  const float* w1 = (sel < 2) ? n1w1 : n2w1;
  const int rb = (sel & 1) * KDIM;
  const int jg = tid & 31, bg = tid >> 5;
  float acc[2][4];
  #pragma unroll
  for (int bi = 0; bi < 2; ++bi)
    #pragma unroll
    for (int ji = 0; ji < 4; ++ji) acc[bi][ji] = 0.f;

  for (int kh = 0; kh < 2; ++kh) {
    __syncthreads();
    for (int e = tid; e < 1600; e += 256) {
      const int k = e >> 5, s = e & 31;
      float4 v;
      if (s < 25) v = ((const float4*)(w1 + (size_t)(rb + kh * 50 + k) * KDIM))[s];
      else        v = make_float4(0.f, 0.f, 0.f, 0.f);
      *(float4*)&W1S[k][4 * s] = v;
    }
    __syncthreads();
    #pragma unroll 2
    for (int k = 0; k < 50; ++k) {
      const f32x2 v = *(const f32x2*)&VT[kh * 50 + k][2 * bg];
      const float4 w = *(const float4*)&W1S[k][4 * jg];
      const float ww[4] = {w.x, w.y, w.z, w.w};
      #pragma unroll
      for (int ji = 0; ji < 4; ++ji) {
        acc[0][ji] = fmaf(v[0], ww[ji], acc[0][ji]);
        acc[1][ji] = fmaf(v[1], ww[ji], acc[1][ji]);
      }
    }
  }

  #pragma unroll
  for (int bi = 0; bi < 2; ++bi) {
    const int b = b0 + 2 * bg + bi;
    if (b < B) {
      float4 o = make_float4(acc[bi][0], acc[bi][1], acc[bi][2], acc[bi][3]);
      *(float4*)(PAG + ((size_t)sel * B + b) * 128 + 4 * jg) = o;
    }
  }
  {
    const int bl = tid >> 4, strip = tid & 15;
    const int b = b0 + bl;
    if (b < B) {
      float* dst = VG + ((size_t)sel * B + b) * KDIM;
      #pragma unroll
      for (int i = 0; i < 7; ++i) {
        const int k = strip + 16 * i;
        if (k < KDIM) dst[k] = VT[k][bl];
      }
    }
  }
}

// ---------------- kernel 3: 256-thread swapped-operand MFMA chain ----------------
// 4 waves; wave wv: net = wv>>1, quarter-pair qp = wv&1 -> quarters {2qp, 2qp+1}
// processed serially (registers reused). Same per-quarter math as the 51.7us R15
// kernel; finer block granularity (4 waves, 18.6KB LDS) to raise waves/CU.
__global__ void __launch_bounds__(256, 4) mlp_kernel(
    const float* __restrict__ VG, const float* __restrict__ PAG,
    const float* __restrict__ tail,
    const float* __restrict__ n1b5, const float* __restrict__ n2b5,
    const __bf16* __restrict__ wfrag, float* __restrict__ out, int B)
{
  __shared__ __align__(16) char smem[SM_BYTES];
  float* sm = (float*)smem;
  const int tid  = threadIdx.x;
  const int lane = tid & 63;
  const int wv   = tid >> 6;     // 0..3
  const int g    = lane >> 4;
  const int c16  = lane & 15;
  const int b    = blockIdx.x;
  const f32x2 Z2 = {0.f, 0.f};

  // ---- phase 0: stage PA + tail + V (small, coalesced)
  if (tid < 128) {
    const int sel = tid >> 5, s = tid & 31;
    *(float4*)&sm[L_PA + sel * 128 + 4 * s] =
        *(const float4*)(PAG + ((size_t)sel * B + b) * 128 + 4 * s);
  } else {
    const int t = tid - 128;
    *(float4*)&sm[L_TAIL + 4 * t] = *(const float4*)(tail + 4 * t);
  }
  if (tid < 200) {
    const int sel = tid / 50, r = tid % 50;
    *(f32x2*)&sm[L_VEC + sel * 100 + 2 * r] =
        *(const f32x2*)(VG + ((size_t)sel * B + b) * KDIM + 2 * r);
  }
  __syncthreads();

  const int net = wv >> 1;
  const int qp  = wv & 1;
  const int vA  = net ? (L_VEC + 0)   : (L_VEC + 200);  // net1: sums, net0: scores
  const int vB  = net ? (L_VEC + 100) : (L_VEC + 300);
  const int pAo = L_PA + net * 256;
  const int pBo = pAo + 128;
  const char* wfb = (const char*)wfrag + net * 21 * 1024;  // global frag base (L2-hot)
  char* h2t = smem + H2T_BYTE + wv * 2048;  // [16 rows][128 B], swizzled
  char* h3t = smem + H3T_BYTE + wv * 1024;  // [16 rows][64 B], swizzled
  const float b5v = net ? n2b5[0] : n1b5[0];
  const int t7 = c16 & 7, t3 = c16 & 3;

  for (int qq = 0; qq < 2; ++qq) {
    const int q  = 2 * qp + qq;
    const int r0 = 25 * q;

    float sAr[2], sBr[2];
    #pragma unroll
    for (int c = 0; c < 2; ++c) {
      const int row = r0 + 16 * c + c16;
      const int rr = row < KDIM ? row : (KDIM - 1);   // clamp; pad rows filtered at write
      sAr[c] = sm[vA + rr]; sBr[c] = sm[vB + rr];
    }

    // ---- layer 2: acc2[chunk][mt] += mfma(W2T[mt][ks], h1frag[chunk][ks])
    f32x4 acc2[2][4];
    #pragma unroll
    for (int c = 0; c < 2; ++c)
      #pragma unroll
      for (int mt = 0; mt < 4; ++mt) acc2[c][mt] = (f32x4){0.f, 0.f, 0.f, 0.f};

    #pragma unroll
    for (int ks = 0; ks < 4; ++ks) {
      const int jb = 32 * ks + 8 * g;
      const f32x2* pa2 = (const f32x2*)&sm[pAo + jb];
      const f32x2* pb2 = (const f32x2*)&sm[pBo + jb];
      const f32x2* b12 = (const f32x2*)&sm[L_TAIL + net * 128 + jb];
      f32x2 paf[4], pbf[4], b1f[4];
      #pragma unroll
      for (int i = 0; i < 4; ++i) { paf[i] = pa2[i]; pbf[i] = pb2[i]; b1f[i] = b12[i]; }
      bf16x8 hb[2];
      #pragma unroll
      for (int c = 0; c < 2; ++c) {
        const f32x2 sa = {sAr[c], sAr[c]}, sb = {sBr[c], sBr[c]};
        bf16x8 a;
        #pragma unroll
        for (int i2 = 0; i2 < 4; ++i2) {
          f32x2 t = sb * pbf[i2] + b1f[i2];   // v_pk_fma_f32 (contracted)
          t = sa * paf[i2] + t;               // v_pk_fma_f32
          t = vmax2(t, Z2);
          a[2 * i2]     = (__bf16)t[0];       // paired -> v_cvt_pk_bf16_f32
          a[2 * i2 + 1] = (__bf16)t[1];
        }
        hb[c] = a;
      }
      __builtin_amdgcn_s_setprio(1);
      #pragma unroll
      for (int mt = 0; mt < 4; ++mt) {
        const bf16x8 a = *(const bf16x8*)(wfb + (mt * 4 + ks) * 1024 + lane * 16);
        acc2[0][mt] = __builtin_amdgcn_mfma_f32_16x16x32_bf16(a, hb[0], acc2[0][mt], 0, 0, 0);
        acc2[1][mt] = __builtin_amdgcn_mfma_f32_16x16x32_bf16(a, hb[1], acc2[1][mt], 0, 0, 0);
      }
      __builtin_amdgcn_s_setprio(0);
    }

    // ---- per-chunk: h2 epilogue -> L3 -> h3 epilogue -> L4+L5
    #pragma unroll
    for (int c = 0; c < 2; ++c) {
      #pragma unroll
      for (int mt = 0; mt < 4; ++mt) {
        const f32x2* b2p = (const f32x2*)&sm[L_TAIL + 256 + net * 64 + 16 * mt + 4 * g];
        const f32x4 x = acc2[c][mt];
        const f32x2 lo = vmax2((f32x2){x[0], x[1]} + b2p[0], Z2);
        const f32x2 hi = vmax2((f32x2){x[2], x[3]} + b2p[1], Z2);
        union { __bf16 e[4]; u32x2 w; } o;
        o.e[0] = (__bf16)lo[0]; o.e[1] = (__bf16)lo[1];
        o.e[2] = (__bf16)hi[0]; o.e[3] = (__bf16)hi[1];
        const int S = (2 * mt + (g >> 1)) ^ t7;
        *(u32x2*)(h2t + c16 * 128 + S * 16 + (g & 1) * 8) = o.w;
      }

      // layer 3: h3^T = W3^T @ h2^T
      f32x4 acc3[2];
      #pragma unroll
      for (int mt = 0; mt < 2; ++mt) acc3[mt] = (f32x4){0.f, 0.f, 0.f, 0.f};
      #pragma unroll
      for (int ks = 0; ks < 2; ++ks) {
        const int S = (4 * ks + g) ^ t7;
        const bf16x8 hbf = *(const bf16x8*)(h2t + c16 * 128 + S * 16);
        __builtin_amdgcn_s_setprio(1);
        #pragma unroll
        for (int mt = 0; mt < 2; ++mt) {
          const bf16x8 a = *(const bf16x8*)(wfb + (16 + mt * 2 + ks) * 1024 + lane * 16);
          acc3[mt] = __builtin_amdgcn_mfma_f32_16x16x32_bf16(a, hbf, acc3[mt], 0, 0, 0);
        }
        __builtin_amdgcn_s_setprio(0);
      }
      #pragma unroll
      for (int mt = 0; mt < 2; ++mt) {
        const f32x2* b3p = (const f32x2*)&sm[L_TAIL + 384 + net * 32 + 16 * mt + 4 * g];
        const f32x4 x = acc3[mt];
        const f32x2 lo = vmax2((f32x2){x[0], x[1]} + b3p[0], Z2);
        const f32x2 hi = vmax2((f32x2){x[2], x[3]} + b3p[1], Z2);
        union { __bf16 e[4]; u32x2 w; } o;
        o.e[0] = (__bf16)lo[0]; o.e[1] = (__bf16)lo[1];
        o.e[2] = (__bf16)hi[0]; o.e[3] = (__bf16)hi[1];
        const int S = (2 * mt + (g >> 1)) ^ t3;
        *(u32x2*)(h3t + c16 * 64 + S * 16 + (g & 1) * 8) = o.w;
      }

      // layer 4 + 5 + per-row reduce
      {
        const int S = g ^ t3;
        const bf16x8 hbf = *(const bf16x8*)(h3t + c16 * 64 + S * 16);
        const bf16x8 a = *(const bf16x8*)(wfb + 20 * 1024 + lane * 16);
        const f32x4 z = {0.f, 0.f, 0.f, 0.f};
        __builtin_amdgcn_s_setprio(1);
        const f32x4 acc4 = __builtin_amdgcn_mfma_f32_16x16x32_bf16(a, hbf, z, 0, 0, 0);
        __builtin_amdgcn_s_setprio(0);
        const f32x2* b4p = (const f32x2*)&sm[L_TAIL + 448 + net * 16 + 4 * g];
        const f32x2* w5p = (const f32x2*)&sm[L_TAIL + 480 + net * 16 + 4 * g];
        const f32x2 lo = vmax2((f32x2){acc4[0], acc4[1]} + b4p[0], Z2);
        const f32x2 hi = vmax2((f32x2){acc4[2], acc4[3]} + b4p[1], Z2);
        float v = lo[0] * w5p[0][0] + lo[1] * w5p[0][1]
                + hi[0] * w5p[1][0] + hi[1] * w5p[1][1];   // pad cols: b4=w5=0
        v += __shfl_xor(v, 16); v += __shfl_xor(v, 32);
        const int lr = 16 * c + c16;
        if (g == 0 && lr < 25)
          sm[L_C + net * 128 + r0 + lr] = v + b5v;
      }
    }
  }
  __syncthreads();

  // ---- final: sum rows 0..99 of both nets -> sigmoid(mean)
  float v = 0.f;
  if (tid < KDIM) v = sm[L_C + tid] + sm[L_C + 128 + tid];
  if (tid < 128) {
    #pragma unroll
    for (int d = 1; d < 64; d <<= 1) v += __shfl_xor(v, d);
    if ((tid & 63) == 0) sm[tid >> 6] = v;
  }
  __syncthreads();
  if (tid == 0) out[b] = 1.f / (1.f + expf(-0.01f * (sm[0] + sm[1])));
}

extern "C" void kernel_launch(void* const* d_in, const int* in_sizes, int n_in,
                              void* d_out, int out_size, void* d_ws, size_t ws_size,
                              hipStream_t stream) {
  const int*   user_idxs = (const int*)d_in[0];
  const int*   item_idxs = (const int*)d_in[1];
  const int*   uidx_t    = (const int*)d_in[2];
  const int*   iidx_t    = (const int*)d_in[3];
  const float* uscr      = (const float*)d_in[4];
  const float* iscr      = (const float*)d_in[5];
  const float* uemb      = (const float*)d_in[6];
  const float* iemb      = (const float*)d_in[7];

  const int B  = in_sizes[0];
  const int NU = in_sizes[6] / DDIM;
  const int NI = in_sizes[7] / DDIM;

  Weights N1 { (const float*)d_in[8],  (const float*)d_in[9],
               (const float*)d_in[10], (const float*)d_in[11],
               (const float*)d_in[12], (const float*)d_in[13],
               (const float*)d_in[14], (const float*)d_in[15],
               (const float*)d_in[16], (const float*)d_in[17] };
  Weights N2 { (const float*)d_in[18], (const float*)d_in[19],
               (const float*)d_in[20], (const float*)d_in[21],
               (const float*)d_in[22], (const float*)d_in[23],
               (const float*)d_in[24], (const float*)d_in[25],
               (const float*)d_in[26], (const float*)d_in[27] };

  char* ws = (char*)d_ws;
  float* u_rowsum = (float*)ws;
  float* i_rowsum = u_rowsum + NU;
  size_t off = (((size_t)(NU + NI) * 4 + 1023) & ~(size_t)1023);
  __bf16* wfrag = (__bf16*)(ws + off);                 // 42*512 bf16 = 43008 B
  float*  tail  = (float*)(wfrag + (size_t)42 * 512);  // 512 f32
  off += (((size_t)42 * 512 * 2 + 512 * 4 + 1023) & ~(size_t)1023);
  float* VG  = (float*)(ws + off);                     // [4][B][100]
  off += (size_t)4 * B * KDIM * 4;
  float* PAG = (float*)(ws + off);                     // [4][B][128]

  float* out = (float*)d_out;

  prep_kernel<<<1024, 256, 0, stream>>>(uemb, iemb, u_rowsum, i_rowsum, NU, NI, N1, N2, wfrag, tail);
  const int nbt = (B + 15) / 16;
  proj_kernel<<<nbt * 4, 256, 0, stream>>>(user_idxs, item_idxs, uidx_t, iidx_t,
                                           uscr, iscr, u_rowsum, i_rowsum,
                                           N1.w1, N2.w1, VG, PAG, B);
  mlp_kernel<<<B, 256, 0, stream>>>(VG, PAG, tail, N1.b5, N2.b5, wfrag, out, B);
}

// Round 23
// 76.183 us; speedup vs baseline: 1.4664x; 1.0086x over previous
//
#include <hip/hip_runtime.h>
#include <math.h>

#define KDIM 100
#define DDIM 64

typedef __bf16 bf16x8 __attribute__((ext_vector_type(8)));
typedef float  f32x4  __attribute__((ext_vector_type(4)));
typedef float  f32x2  __attribute__((ext_vector_type(2)));
typedef unsigned int u32;
typedef u32 u32x2 __attribute__((ext_vector_type(2)));

struct Weights {
  const float *w1, *b1, *w2, *b2, *w3, *b3, *w4, *b4, *w5, *b5;
};

__device__ __forceinline__ f32x2 vmax2(f32x2 a, f32x2 b) {
#if __has_builtin(__builtin_elementwise_max)
  return __builtin_elementwise_max(a, b);
#else
  return (f32x2){fmaxf(a[0], b[0]), fmaxf(a[1], b[1])};
#endif
}

// ---------------- mlp LDS layout (256 threads, 4 waves, 2 quarters/wave interleaved) ----------------
// floats: L_VEC [4][100] | L_PA [4][128] | L_TAIL [512] | L_C [2][128]
constexpr int L_VEC  = 0;
constexpr int L_PA   = 400;
constexpr int L_TAIL = 912;   // b1[2][128]@0 b2[2][64]@256 b3[2][32]@384 b4[2][16]@448 w5[2][16]@480
constexpr int L_C    = 1424;
constexpr int SM_F   = 1680;                     // 6720 B
constexpr int H2T_BYTE = SM_F * 4;               // 6720; (4 wv x 2 qt) x 16 rows x 128 B
constexpr int H3T_BYTE = H2T_BYTE + 8 * 2048;    // 23104; (4 wv x 2 qt) x 16 rows x 64 B
constexpr int SM_BYTES = H3T_BYTE + 8 * 1024;    // 31296 B -> 5 blocks/CU by LDS

// ---------------- kernel 1: rowsums + transposed A-frag pack + bias tail ----------------
// wfrag: [net(2)][frag f(21)][lane(64)][8 bf16].
// f 0-15:  W2^T A-frag (mt=f>>2, ks=f&3): elem i = w2[32ks+8g+i][16mt+c16]
// f 16-19: W3^T (mt=(f-16)>>1, ks=(f-16)&1): elem i = w3[32ks+8g+i][16mt+c16]
// f 20:    W4^T: elem i = w4[8g+i][c16]
__global__ void prep_kernel(const float* __restrict__ user_emb,
                            const float* __restrict__ item_emb,
                            float* __restrict__ u_rowsum,
                            float* __restrict__ i_rowsum,
                            int NU, int NI, Weights N1, Weights N2,
                            __bf16* __restrict__ wfrag, float* __restrict__ tail) {
  const int tid  = threadIdx.x;
  const int lane = tid & 63;
  const int g = lane >> 4, c16 = lane & 15;
  const int gw = (blockIdx.x * blockDim.x + tid) >> 6;

  if (gw < 42) {
    const int net = gw / 21, f = gw % 21;
    const Weights W = net ? N2 : N1;
    bf16x8 v;
    if (f < 16) {
      const int mt = f >> 2, ks = f & 3;
      #pragma unroll
      for (int i = 0; i < 8; ++i) {
        const int k = 32 * ks + 8 * g + i, m = 16 * mt + c16;
        v[i] = (__bf16)((k < 100 && m < 50) ? W.w2[k * 50 + m] : 0.f);
      }
    } else if (f < 20) {
      const int mt = (f - 16) >> 1, ks = (f - 16) & 1;
      #pragma unroll
      for (int i = 0; i < 8; ++i) {
        const int k = 32 * ks + 8 * g + i, m = 16 * mt + c16;
        v[i] = (__bf16)((k < 50 && m < 25) ? W.w3[k * 25 + m] : 0.f);
      }
    } else {
      #pragma unroll
      for (int i = 0; i < 8; ++i) {
        const int k = 8 * g + i, m = c16;
        v[i] = (__bf16)((k < 25 && m < 12) ? W.w4[k * 12 + m] : 0.f);
      }
    }
    *(bf16x8*)(wfrag + (size_t)gw * 512 + lane * 8) = v;
  }

  if (blockIdx.x == 0) {
    for (int e = tid; e < 512; e += 256) {
      float v;
      if (e < 256)      { const int j = e & 127; const Weights W = (e & 128) ? N2 : N1; v = (j < 100) ? W.b1[j] : 0.f; }
      else if (e < 384) { const int t = e - 256; const int j = t & 63; const Weights W = (t & 64) ? N2 : N1; v = (j < 50) ? W.b2[j] : 0.f; }
      else if (e < 448) { const int t = e - 384; const int j = t & 31; const Weights W = (t & 32) ? N2 : N1; v = (j < 25) ? W.b3[j] : 0.f; }
      else if (e < 480) { const int t = e - 448; const int j = t & 15; const Weights W = (t & 16) ? N2 : N1; v = (j < 12) ? W.b4[j] : 0.f; }
      else              { const int t = e - 480; const int j = t & 15; const Weights W = (t & 16) ? N2 : N1; v = (j < 12) ? W.w5[j] : 0.f; }
      tail[e] = v;
    }
  }

  const int NR = NU + NI;
  const int chunk = lane & 15, lrow = lane >> 4;
  const int nwave = (gridDim.x * blockDim.x) >> 6;
  for (int base = gw * 4; base < NR; base += nwave * 4) {
    const int r = base + lrow;
    float s = 0.f;
    if (r < NR) {
      const float* src = (r < NU) ? (user_emb + (size_t)r * DDIM)
                                  : (item_emb + (size_t)(r - NU) * DDIM);
      const float4 v4 = ((const float4*)src)[chunk];
      s = v4.x + v4.y + v4.z + v4.w;
    }
    s += __shfl_xor(s, 1); s += __shfl_xor(s, 2);
    s += __shfl_xor(s, 4); s += __shfl_xor(s, 8);
    if (chunk == 0 && r < NR) {
      if (r < NU) u_rowsum[r] = s; else i_rowsum[r - NU] = s;
    }
  }
}

// ---------------- kernel 2: batched layer-1 projections (TILE_B = 16) ----------------
__global__ void __launch_bounds__(256) proj_kernel(
    const int* __restrict__ user_idxs, const int* __restrict__ item_idxs,
    const int* __restrict__ uidx_t, const int* __restrict__ iidx_t,
    const float* __restrict__ uscr, const float* __restrict__ iscr,
    const float* __restrict__ u_rowsum, const float* __restrict__ i_rowsum,
    const float* __restrict__ n1w1, const float* __restrict__ n2w1,
    float* __restrict__ VG, float* __restrict__ PAG, int B)
{
  __shared__ float VT[100][20];
  __shared__ float W1S[50][128];
  __shared__ int sidx[16];
  const int tid = threadIdx.x;
  const int sel = blockIdx.x & 3;
  const int b0  = (blockIdx.x >> 2) * 16;

  if (tid < 16) {
    const int b = b0 + tid;
    const int bb = (b < B) ? b : (B - 1);
    sidx[tid] = (sel & 1) ? item_idxs[bb] : user_idxs[bb];
  }
  __syncthreads();

  {
    const int bl = tid >> 4, strip = tid & 15;
    const size_t row = (size_t)sidx[bl] * KDIM;
    if (sel < 2) {
      const int* it = (sel == 0) ? uidx_t : iidx_t;
      const float* rs = (sel == 0) ? u_rowsum : i_rowsum;
      int idxs[7];
      #pragma unroll
      for (int i = 0; i < 7; ++i) {
        const int k = strip + 16 * i;
        idxs[i] = (k < KDIM) ? it[row + k] : 0;
      }
      #pragma unroll
      for (int i = 0; i < 7; ++i) {
        const int k = strip + 16 * i;
        if (k < KDIM) VT[k][bl] = rs[idxs[i]];
      }
    } else {
      const float* sc = (sel == 2) ? uscr : iscr;
      #pragma unroll
      for (int i = 0; i < 7; ++i) {
        const int k = strip + 16 * i;
        if (k < KDIM) VT[k][bl] = sc[row + k];
      }
    }
  }

  const float* w1 = (sel < 2) ? n1w1 : n2w1;
  const int rb = (sel & 1) * KDIM;
  const int jg = tid & 31, bg = tid >> 5;
  float acc[2][4];
  #pragma unroll
  for (int bi = 0; bi < 2; ++bi)
    #pragma unroll
    for (int ji = 0; ji < 4; ++ji) acc[bi][ji] = 0.f;

  for (int kh = 0; kh < 2; ++kh) {
    __syncthreads();
    for (int e = tid; e < 1600; e += 256) {
      const int k = e >> 5, s = e & 31;
      float4 v;
      if (s < 25) v = ((const float4*)(w1 + (size_t)(rb + kh * 50 + k) * KDIM))[s];
      else        v = make_float4(0.f, 0.f, 0.f, 0.f);
      *(float4*)&W1S[k][4 * s] = v;
    }
    __syncthreads();
    #pragma unroll 2
    for (int k = 0; k < 50; ++k) {
      const f32x2 v = *(const f32x2*)&VT[kh * 50 + k][2 * bg];
      const float4 w = *(const float4*)&W1S[k][4 * jg];
      const float ww[4] = {w.x, w.y, w.z, w.w};
      #pragma unroll
      for (int ji = 0; ji < 4; ++ji) {
        acc[0][ji] = fmaf(v[0], ww[ji], acc[0][ji]);
        acc[1][ji] = fmaf(v[1], ww[ji], acc[1][ji]);
      }
    }
  }

  #pragma unroll
  for (int bi = 0; bi < 2; ++bi) {
    const int b = b0 + 2 * bg + bi;
    if (b < B) {
      float4 o = make_float4(acc[bi][0], acc[bi][1], acc[bi][2], acc[bi][3]);
      *(float4*)(PAG + ((size_t)sel * B + b) * 128 + 4 * jg) = o;
    }
  }
  {
    const int bl = tid >> 4, strip = tid & 15;
    const int b = b0 + bl;
    if (b < B) {
      float* dst = VG + ((size_t)sel * B + b) * KDIM;
      #pragma unroll
      for (int i = 0; i < 7; ++i) {
        const int k = strip + 16 * i;
        if (k < KDIM) dst[k] = VT[k][bl];
      }
    }
  }
}

// ---------------- kernel 3: quarter-interleaved swapped-operand MFMA chain ----------------
// 256 threads = 4 waves; wave wv: net = wv>>1, qp = wv&1 -> quarters {2qp, 2qp+1}
// processed CONCURRENTLY (independent chains = ILP vs latency); frag/PA/bias loads
// shared across the two quarters. Per-(wave,qt) transpose buffers.
__global__ void __launch_bounds__(256, 3) mlp_kernel(
    const float* __restrict__ VG, const float* __restrict__ PAG,
    const float* __restrict__ tail,
    const float* __restrict__ n1b5, const float* __restrict__ n2b5,
    const __bf16* __restrict__ wfrag, float* __restrict__ out, int B)
{
  __shared__ __align__(16) char smem[SM_BYTES];
  float* sm = (float*)smem;
  const int tid  = threadIdx.x;
  const int lane = tid & 63;
  const int wv   = tid >> 6;     // 0..3
  const int g    = lane >> 4;
  const int c16  = lane & 15;
  const int b    = blockIdx.x;
  const f32x2 Z2 = {0.f, 0.f};

  // ---- phase 0: stage PA + tail + V (small, coalesced)
  if (tid < 128) {
    const int sel = tid >> 5, s = tid & 31;
    *(float4*)&sm[L_PA + sel * 128 + 4 * s] =
        *(const float4*)(PAG + ((size_t)sel * B + b) * 128 + 4 * s);
  } else {
    const int t = tid - 128;
    *(float4*)&sm[L_TAIL + 4 * t] = *(const float4*)(tail + 4 * t);
  }
  if (tid < 200) {
    const int sel = tid / 50, r = tid % 50;
    *(f32x2*)&sm[L_VEC + sel * 100 + 2 * r] =
        *(const f32x2*)(VG + ((size_t)sel * B + b) * KDIM + 2 * r);
  }
  __syncthreads();

  const int net = wv >> 1;
  const int qp  = wv & 1;
  const int vA  = net ? (L_VEC + 0)   : (L_VEC + 200);  // net1: sums, net0: scores
  const int vB  = net ? (L_VEC + 100) : (L_VEC + 300);
  const int pAo = L_PA + net * 256;
  const int pBo = pAo + 128;
  const char* wfb = (const char*)wfrag + net * 21 * 1024;  // global frag base (L2-hot)
  char* h2t0 = smem + H2T_BYTE + (wv * 2 + 0) * 2048;  // [16 rows][128 B], swizzled
  char* h2t1 = smem + H2T_BYTE + (wv * 2 + 1) * 2048;
  char* h3t0 = smem + H3T_BYTE + (wv * 2 + 0) * 1024;  // [16 rows][64 B], swizzled
  char* h3t1 = smem + H3T_BYTE + (wv * 2 + 1) * 1024;
  const float b5v = net ? n2b5[0] : n1b5[0];
  const int t7 = c16 & 7, t3 = c16 & 3;

  // row scalars for both quarters x both chunks
  float sAr[2][2], sBr[2][2];
  #pragma unroll
  for (int qt = 0; qt < 2; ++qt)
    #pragma unroll
    for (int c = 0; c < 2; ++c) {
      const int row = 25 * (2 * qp + qt) + 16 * c + c16;
      const int rr = row < KDIM ? row : (KDIM - 1);   // clamp; pad rows filtered at write
      sAr[qt][c] = sm[vA + rr]; sBr[qt][c] = sm[vB + rr];
    }

  // ---- layer 2: acc2[qt][chunk][mt]; frag/PA/bias loads shared across quarters
  f32x4 acc2[2][2][4];
  #pragma unroll
  for (int qt = 0; qt < 2; ++qt)
    #pragma unroll
    for (int c = 0; c < 2; ++c)
      #pragma unroll
      for (int mt = 0; mt < 4; ++mt) acc2[qt][c][mt] = (f32x4){0.f, 0.f, 0.f, 0.f};

  #pragma unroll
  for (int ks = 0; ks < 4; ++ks) {
    const int jb = 32 * ks + 8 * g;
    const f32x2* pa2 = (const f32x2*)&sm[pAo + jb];
    const f32x2* pb2 = (const f32x2*)&sm[pBo + jb];
    const f32x2* b12 = (const f32x2*)&sm[L_TAIL + net * 128 + jb];
    f32x2 paf[4], pbf[4], b1f[4];
    #pragma unroll
    for (int i = 0; i < 4; ++i) { paf[i] = pa2[i]; pbf[i] = pb2[i]; b1f[i] = b12[i]; }
    bf16x8 hb[2][2];
    #pragma unroll
    for (int qt = 0; qt < 2; ++qt)
      #pragma unroll
      for (int c = 0; c < 2; ++c) {
        const f32x2 sa = {sAr[qt][c], sAr[qt][c]}, sb = {sBr[qt][c], sBr[qt][c]};
        bf16x8 a;
        #pragma unroll
        for (int i2 = 0; i2 < 4; ++i2) {
          f32x2 t = sb * pbf[i2] + b1f[i2];   // v_pk_fma_f32 (contracted)
          t = sa * paf[i2] + t;               // v_pk_fma_f32
          t = vmax2(t, Z2);
          a[2 * i2]     = (__bf16)t[0];       // paired -> v_cvt_pk_bf16_f32
          a[2 * i2 + 1] = (__bf16)t[1];
        }
        hb[qt][c] = a;
      }
    __builtin_amdgcn_s_setprio(1);
    #pragma unroll
    for (int mt = 0; mt < 4; ++mt) {
      const bf16x8 a = *(const bf16x8*)(wfb + (mt * 4 + ks) * 1024 + lane * 16);
      #pragma unroll
      for (int qt = 0; qt < 2; ++qt) {
        acc2[qt][0][mt] = __builtin_amdgcn_mfma_f32_16x16x32_bf16(a, hb[qt][0], acc2[qt][0][mt], 0, 0, 0);
        acc2[qt][1][mt] = __builtin_amdgcn_mfma_f32_16x16x32_bf16(a, hb[qt][1], acc2[qt][1][mt], 0, 0, 0);
      }
    }
    __builtin_amdgcn_s_setprio(0);
  }

  // ---- per-chunk tails: both quarters' chains interleaved (independent)
  #pragma unroll
  for (int c = 0; c < 2; ++c) {
    // h2 epilogues (both quarters)
    #pragma unroll
    for (int qt = 0; qt < 2; ++qt) {
      char* h2t = qt ? h2t1 : h2t0;
      #pragma unroll
      for (int mt = 0; mt < 4; ++mt) {
        const f32x2* b2p = (const f32x2*)&sm[L_TAIL + 256 + net * 64 + 16 * mt + 4 * g];
        const f32x4 x = acc2[qt][c][mt];
        const f32x2 lo = vmax2((f32x2){x[0], x[1]} + b2p[0], Z2);
        const f32x2 hi = vmax2((f32x2){x[2], x[3]} + b2p[1], Z2);
        union { __bf16 e[4]; u32x2 w; } o;
        o.e[0] = (__bf16)lo[0]; o.e[1] = (__bf16)lo[1];
        o.e[2] = (__bf16)hi[0]; o.e[3] = (__bf16)hi[1];
        const int S = (2 * mt + (g >> 1)) ^ t7;
        *(u32x2*)(h2t + c16 * 128 + S * 16 + (g & 1) * 8) = o.w;
      }
    }

    // layer 3 (both quarters)
    f32x4 acc3[2][2];
    #pragma unroll
    for (int qt = 0; qt < 2; ++qt)
      #pragma unroll
      for (int mt = 0; mt < 2; ++mt) acc3[qt][mt] = (f32x4){0.f, 0.f, 0.f, 0.f};
    #pragma unroll
    for (int ks = 0; ks < 2; ++ks) {
      const int S = (4 * ks + g) ^ t7;
      const bf16x8 hbf0 = *(const bf16x8*)(h2t0 + c16 * 128 + S * 16);
      const bf16x8 hbf1 = *(const bf16x8*)(h2t1 + c16 * 128 + S * 16);
      __builtin_amdgcn_s_setprio(1);
      #pragma unroll
      for (int mt = 0; mt < 2; ++mt) {
        const bf16x8 a = *(const bf16x8*)(wfb + (16 + mt * 2 + ks) * 1024 + lane * 16);
        acc3[0][mt] = __builtin_amdgcn_mfma_f32_16x16x32_bf16(a, hbf0, acc3[0][mt], 0, 0, 0);
        acc3[1][mt] = __builtin_amdgcn_mfma_f32_16x16x32_bf16(a, hbf1, acc3[1][mt], 0, 0, 0);
      }
      __builtin_amdgcn_s_setprio(0);
    }
    #pragma unroll
    for (int qt = 0; qt < 2; ++qt) {
      char* h3t = qt ? h3t1 : h3t0;
      #pragma unroll
      for (int mt = 0; mt < 2; ++mt) {
        const f32x2* b3p = (const f32x2*)&sm[L_TAIL + 384 + net * 32 + 16 * mt + 4 * g];
        const f32x4 x = acc3[qt][mt];
        const f32x2 lo = vmax2((f32x2){x[0], x[1]} + b3p[0], Z2);
        const f32x2 hi = vmax2((f32x2){x[2], x[3]} + b3p[1], Z2);
        union { __bf16 e[4]; u32x2 w; } o;
        o.e[0] = (__bf16)lo[0]; o.e[1] = (__bf16)lo[1];
        o.e[2] = (__bf16)hi[0]; o.e[3] = (__bf16)hi[1];
        const int S = (2 * mt + (g >> 1)) ^ t3;
        *(u32x2*)(h3t + c16 * 64 + S * 16 + (g & 1) * 8) = o.w;
      }
    }

    // layer 4 + 5 + per-row reduce (both quarters)
    {
      const int S = g ^ t3;
      const bf16x8 hbf0 = *(const bf16x8*)(h3t0 + c16 * 64 + S * 16);
      const bf16x8 hbf1 = *(const bf16x8*)(h3t1 + c16 * 64 + S * 16);
      const bf16x8 a = *(const bf16x8*)(wfb + 20 * 1024 + lane * 16);
      const f32x4 z = {0.f, 0.f, 0.f, 0.f};
      __builtin_amdgcn_s_setprio(1);
      const f32x4 acc4_0 = __builtin_amdgcn_mfma_f32_16x16x32_bf16(a, hbf0, z, 0, 0, 0);
      const f32x4 acc4_1 = __builtin_amdgcn_mfma_f32_16x16x32_bf16(a, hbf1, z, 0, 0, 0);
      __builtin_amdgcn_s_setprio(0);
      const f32x2* b4p = (const f32x2*)&sm[L_TAIL + 448 + net * 16 + 4 * g];
      const f32x2* w5p = (const f32x2*)&sm[L_TAIL + 480 + net * 16 + 4 * g];
      #pragma unroll
      for (int qt = 0; qt < 2; ++qt) {
        const f32x4 x = qt ? acc4_1 : acc4_0;
        const f32x2 lo = vmax2((f32x2){x[0], x[1]} + b4p[0], Z2);
        const f32x2 hi = vmax2((f32x2){x[2], x[3]} + b4p[1], Z2);
        float v = lo[0] * w5p[0][0] + lo[1] * w5p[0][1]
                + hi[0] * w5p[1][0] + hi[1] * w5p[1][1];   // pad cols: b4=w5=0
        v += __shfl_xor(v, 16); v += __shfl_xor(v, 32);
        const int lr = 16 * c + c16;
        if (g == 0 && lr < 25)
          sm[L_C + net * 128 + 25 * (2 * qp + qt) + lr] = v + b5v;
      }
    }
  }
  __syncthreads();

  // ---- final: sum rows 0..99 of both nets -> sigmoid(mean)
  float v = 0.f;
  if (tid < KDIM) v = sm[L_C + tid] + sm[L_C + 128 + tid];
  if (tid < 128) {
    #pragma unroll
    for (int d = 1; d < 64; d <<= 1) v += __shfl_xor(v, d);
    if ((tid & 63) == 0) sm[tid >> 6] = v;
  }
  __syncthreads();
  if (tid == 0) out[b] = 1.f / (1.f + expf(-0.01f * (sm[0] + sm[1])));
}

extern "C" void kernel_launch(void* const* d_in, const int* in_sizes, int n_in,
                              void* d_out, int out_size, void* d_ws, size_t ws_size,
                              hipStream_t stream) {
  const int*   user_idxs = (const int*)d_in[0];
  const int*   item_idxs = (const int*)d_in[1];
  const int*   uidx_t    = (const int*)d_in[2];
  const int*   iidx_t    = (const int*)d_in[3];
  const float* uscr      = (const float*)d_in[4];
  const float* iscr      = (const float*)d_in[5];
  const float* uemb      = (const float*)d_in[6];
  const float* iemb      = (const float*)d_in[7];

  const int B  = in_sizes[0];
  const int NU = in_sizes[6] / DDIM;
  const int NI = in_sizes[7] / DDIM;

  Weights N1 { (const float*)d_in[8],  (const float*)d_in[9],
               (const float*)d_in[10], (const float*)d_in[11],
               (const float*)d_in[12], (const float*)d_in[13],
               (const float*)d_in[14], (const float*)d_in[15],
               (const float*)d_in[16], (const float*)d_in[17] };
  Weights N2 { (const float*)d_in[18], (const float*)d_in[19],
               (const float*)d_in[20], (const float*)d_in[21],
               (const float*)d_in[22], (const float*)d_in[23],
               (const float*)d_in[24], (const float*)d_in[25],
               (const float*)d_in[26], (const float*)d_in[27] };

  char* ws = (char*)d_ws;
  float* u_rowsum = (float*)ws;
  float* i_rowsum = u_rowsum + NU;
  size_t off = (((size_t)(NU + NI) * 4 + 1023) & ~(size_t)1023);
  __bf16* wfrag = (__bf16*)(ws + off);                 // 42*512 bf16 = 43008 B
  float*  tail  = (float*)(wfrag + (size_t)42 * 512);  // 512 f32
  off += (((size_t)42 * 512 * 2 + 512 * 4 + 1023) & ~(size_t)1023);
  float* VG  = (float*)(ws + off);                     // [4][B][100]
  off += (size_t)4 * B * KDIM * 4;
  float* PAG = (float*)(ws + off);                     // [4][B][128]

  float* out = (float*)d_out;

  prep_kernel<<<1024, 256, 0, stream>>>(uemb, iemb, u_rowsum, i_rowsum, NU, NI, N1, N2, wfrag, tail);
  const int nbt = (B + 15) / 16;
  proj_kernel<<<nbt * 4, 256, 0, stream>>>(user_idxs, item_idxs, uidx_t, iidx_t,
                                           uscr, iscr, u_rowsum, i_rowsum,
                                           N1.w1, N2.w1, VG, PAG, B);
  mlp_kernel<<<B, 256, 0, stream>>>(VG, PAG, tail, N1.b5, N2.b5, wfrag, out, B);
}

// Round 24
// 68.946 us; speedup vs baseline: 1.6203x; 1.1050x over previous
//
#include <hip/hip_runtime.h>
#include <math.h>

#define KDIM 100
#define DDIM 64

typedef __bf16 bf16x8 __attribute__((ext_vector_type(8)));
typedef float  f32x4  __attribute__((ext_vector_type(4)));
typedef float  f32x2  __attribute__((ext_vector_type(2)));
typedef unsigned int u32;
typedef u32 u32x2 __attribute__((ext_vector_type(2)));

struct Weights {
  const float *w1, *b1, *w2, *b2, *w3, *b3, *w4, *b4, *w5, *b5;
};

__device__ __forceinline__ f32x2 vmax2(f32x2 a, f32x2 b) {
#if __has_builtin(__builtin_elementwise_max)
  return __builtin_elementwise_max(a, b);
#else
  return (f32x2){fmaxf(a[0], b[0]), fmaxf(a[1], b[1])};
#endif
}

// ---------------- mlp LDS layout (256 threads, 4 waves, 2 quarters/wave interleaved) ----------------
// floats: L_VEC [4][100] | L_PA [4][128] | L_TAIL [512] | L_C [2][128]
constexpr int L_VEC  = 0;
constexpr int L_PA   = 400;
constexpr int L_TAIL = 912;   // b1[2][128]@0 b2[2][64]@256 b3[2][32]@384 b4[2][16]@448 w5[2][16]@480
constexpr int L_C    = 1424;
constexpr int SM_F   = 1680;                     // 6720 B
constexpr int H2T_BYTE = SM_F * 4;               // 6720; (4 wv x 2 qt) x 16 rows x 128 B
constexpr int H3T_BYTE = H2T_BYTE + 8 * 2048;    // 23104; (4 wv x 2 qt) x 16 rows x 64 B
constexpr int SM_BYTES = H3T_BYTE + 8 * 1024;    // 31296 B

// ---------------- kernel 1: rowsums + frag packing (weights + w1) + bias tail ----------------
// wfrag: [net(2)][frag f(21)][lane(64)][8 bf16]  (layers 2-4, W^T A-frags)
// w1frag: [sel(4)][mt(8)][ks(4)][lane(64)][8 bf16]: elem i = w1sel[(rb+32ks+8g+i)][16mt+c16]
//         (w1^T A-frags for the MFMA proj; k/n pads -> 0)
__global__ void prep_kernel(const float* __restrict__ user_emb,
                            const float* __restrict__ item_emb,
                            float* __restrict__ u_rowsum,
                            float* __restrict__ i_rowsum,
                            int NU, int NI, Weights N1, Weights N2,
                            __bf16* __restrict__ wfrag, float* __restrict__ tail,
                            __bf16* __restrict__ w1frag) {
  const int tid  = threadIdx.x;
  const int lane = tid & 63;
  const int g = lane >> 4, c16 = lane & 15;
  const int gw = (blockIdx.x * blockDim.x + tid) >> 6;

  if (gw < 42) {
    const int net = gw / 21, f = gw % 21;
    const Weights W = net ? N2 : N1;
    bf16x8 v;
    if (f < 16) {
      const int mt = f >> 2, ks = f & 3;
      #pragma unroll
      for (int i = 0; i < 8; ++i) {
        const int k = 32 * ks + 8 * g + i, m = 16 * mt + c16;
        v[i] = (__bf16)((k < 100 && m < 50) ? W.w2[k * 50 + m] : 0.f);
      }
    } else if (f < 20) {
      const int mt = (f - 16) >> 1, ks = (f - 16) & 1;
      #pragma unroll
      for (int i = 0; i < 8; ++i) {
        const int k = 32 * ks + 8 * g + i, m = 16 * mt + c16;
        v[i] = (__bf16)((k < 50 && m < 25) ? W.w3[k * 25 + m] : 0.f);
      }
    } else {
      #pragma unroll
      for (int i = 0; i < 8; ++i) {
        const int k = 8 * g + i, m = c16;
        v[i] = (__bf16)((k < 25 && m < 12) ? W.w4[k * 12 + m] : 0.f);
      }
    }
    *(bf16x8*)(wfrag + (size_t)gw * 512 + lane * 8) = v;
  } else if (gw < 170) {
    // pack w1^T A-frags for the MFMA proj
    const int t = gw - 42;            // 0..127 = sel*32 + mt*4 + ks
    const int sel = t >> 5;
    const int f = t & 31;
    const int mt = f >> 2, ks = f & 3;
    const float* w1 = (sel < 2) ? N1.w1 : N2.w1;
    const int rb = (sel & 1) * KDIM;
    bf16x8 v;
    #pragma unroll
    for (int i = 0; i < 8; ++i) {
      const int k = 32 * ks + 8 * g + i, n = 16 * mt + c16;
      v[i] = (__bf16)((k < KDIM && n < KDIM) ? w1[(size_t)(rb + k) * KDIM + n] : 0.f);
    }
    *(bf16x8*)(w1frag + (size_t)t * 512 + lane * 8) = v;
  }

  if (blockIdx.x == 0) {
    for (int e = tid; e < 512; e += 256) {
      float v;
      if (e < 256)      { const int j = e & 127; const Weights W = (e & 128) ? N2 : N1; v = (j < 100) ? W.b1[j] : 0.f; }
      else if (e < 384) { const int t = e - 256; const int j = t & 63; const Weights W = (t & 64) ? N2 : N1; v = (j < 50) ? W.b2[j] : 0.f; }
      else if (e < 448) { const int t = e - 384; const int j = t & 31; const Weights W = (t & 32) ? N2 : N1; v = (j < 25) ? W.b3[j] : 0.f; }
      else if (e < 480) { const int t = e - 448; const int j = t & 15; const Weights W = (t & 16) ? N2 : N1; v = (j < 12) ? W.b4[j] : 0.f; }
      else              { const int t = e - 480; const int j = t & 15; const Weights W = (t & 16) ? N2 : N1; v = (j < 12) ? W.w5[j] : 0.f; }
      tail[e] = v;
    }
  }

  const int NR = NU + NI;
  const int chunk = lane & 15, lrow = lane >> 4;
  const int nwave = (gridDim.x * blockDim.x) >> 6;
  for (int base = gw * 4; base < NR; base += nwave * 4) {
    const int r = base + lrow;
    float s = 0.f;
    if (r < NR) {
      const float* src = (r < NU) ? (user_emb + (size_t)r * DDIM)
                                  : (item_emb + (size_t)(r - NU) * DDIM);
      const float4 v4 = ((const float4*)src)[chunk];
      s = v4.x + v4.y + v4.z + v4.w;
    }
    s += __shfl_xor(s, 1); s += __shfl_xor(s, 2);
    s += __shfl_xor(s, 4); s += __shfl_xor(s, 8);
    if (chunk == 0 && r < NR) {
      if (r < NU) u_rowsum[r] = s; else i_rowsum[r - NU] = s;
    }
  }
}

// ---------------- kernel 2: MFMA layer-1 projections ----------------
// Block = (sel, 16 batches). Gather V[16][<=100] to LDS fp32, then
// PA^T = w1^T @ V^T via 16x16x32 MFMA: A = w1frag (M = out-col n),
// B = V frag (N = batch), D[n = 16mt+4g+r][batch = c16] -> per-lane f32x4 stores.
__global__ void __launch_bounds__(256) proj_kernel(
    const int* __restrict__ user_idxs, const int* __restrict__ item_idxs,
    const int* __restrict__ uidx_t, const int* __restrict__ iidx_t,
    const float* __restrict__ uscr, const float* __restrict__ iscr,
    const float* __restrict__ u_rowsum, const float* __restrict__ i_rowsum,
    const __bf16* __restrict__ w1frag,
    float* __restrict__ VG, float* __restrict__ PAG, int B)
{
  __shared__ float VT[16][132];   // stride 132 -> 2-way-max bank aliasing on row reads
  const int tid = threadIdx.x;
  const int lane = tid & 63;
  const int wv  = tid >> 6;       // 0..3
  const int g = lane >> 4, c16 = lane & 15;
  const int sel = blockIdx.x & 3;
  const int b0  = (blockIdx.x >> 2) * 16;

  // ---- gather V-tile: 16 threads per batch; zero-fill k >= 100 (K-pad for MFMA)
  {
    const int bl = tid >> 4, strip = tid & 15;
    const int b = b0 + bl;
    const int bb = (b < B) ? b : (B - 1);
    const int sb = (sel & 1) ? item_idxs[bb] : user_idxs[bb];
    const size_t row = (size_t)sb * KDIM;
    if (sel == 0) {
      #pragma unroll
      for (int i = 0; i < 8; ++i) {
        const int k = strip + 16 * i;
        VT[bl][k] = (k < KDIM) ? u_rowsum[uidx_t[row + k]] : 0.f;
      }
    } else if (sel == 1) {
      #pragma unroll
      for (int i = 0; i < 8; ++i) {
        const int k = strip + 16 * i;
        VT[bl][k] = (k < KDIM) ? i_rowsum[iidx_t[row + k]] : 0.f;
      }
    } else if (sel == 2) {
      #pragma unroll
      for (int i = 0; i < 8; ++i) {
        const int k = strip + 16 * i;
        VT[bl][k] = (k < KDIM) ? uscr[row + k] : 0.f;
      }
    } else {
      #pragma unroll
      for (int i = 0; i < 8; ++i) {
        const int k = strip + 16 * i;
        VT[bl][k] = (k < KDIM) ? iscr[row + k] : 0.f;
      }
    }
  }
  __syncthreads();

  // ---- VG write-through (fp32 exact, for mlp row scalars)
  {
    const int bl = tid >> 4, strip = tid & 15;
    const int b = b0 + bl;
    if (b < B) {
      float* dst = VG + ((size_t)sel * B + b) * KDIM;
      #pragma unroll
      for (int i = 0; i < 7; ++i) {
        const int k = strip + 16 * i;
        if (k < KDIM) dst[k] = VT[bl][k];
      }
    }
  }

  // ---- B-frags (V): b[i] = V[batch c16][32ks+8g+i], shared across this wave's mt
  bf16x8 bf[4];
  #pragma unroll
  for (int ks = 0; ks < 4; ++ks) {
    const float* src = &VT[c16][32 * ks + 8 * g];
    bf16x8 a;
    #pragma unroll
    for (int i = 0; i < 8; ++i) a[i] = (__bf16)src[i];
    bf[ks] = a;
  }

  // ---- MFMA: wave wv handles n-tiles mt = 2wv, 2wv+1
  f32x4 acc[2];
  #pragma unroll
  for (int m2 = 0; m2 < 2; ++m2) acc[m2] = (f32x4){0.f, 0.f, 0.f, 0.f};
  #pragma unroll
  for (int m2 = 0; m2 < 2; ++m2) {
    const int mt = 2 * wv + m2;
    #pragma unroll
    for (int ks = 0; ks < 4; ++ks) {
      const bf16x8 a = *(const bf16x8*)(w1frag + ((size_t)(sel * 32 + mt * 4 + ks)) * 512 + lane * 8);
      acc[m2] = __builtin_amdgcn_mfma_f32_16x16x32_bf16(a, bf[ks], acc[m2], 0, 0, 0);
    }
  }

  // ---- store PA: D[n = 16mt + 4g + r][batch = c16] -> f32x4 per (lane, mt)
  {
    const int b = b0 + c16;
    if (b < B) {
      #pragma unroll
      for (int m2 = 0; m2 < 2; ++m2) {
        const int mt = 2 * wv + m2;
        *(f32x4*)(PAG + ((size_t)sel * B + b) * 128 + 16 * mt + 4 * g) = acc[m2];
      }
    }
  }
}

// ---------------- kernel 3: quarter-interleaved swapped-operand MFMA chain ----------------
// 256 threads = 4 waves; wave wv: net = wv>>1, qp = wv&1 -> quarters {2qp, 2qp+1}
// processed CONCURRENTLY (independent chains = ILP vs latency); frag/PA/bias loads
// shared across the two quarters. Per-(wave,qt) transpose buffers.
__global__ void __launch_bounds__(256, 3) mlp_kernel(
    const float* __restrict__ VG, const float* __restrict__ PAG,
    const float* __restrict__ tail,
    const float* __restrict__ n1b5, const float* __restrict__ n2b5,
    const __bf16* __restrict__ wfrag, float* __restrict__ out, int B)
{
  __shared__ __align__(16) char smem[SM_BYTES];
  float* sm = (float*)smem;
  const int tid  = threadIdx.x;
  const int lane = tid & 63;
  const int wv   = tid >> 6;     // 0..3
  const int g    = lane >> 4;
  const int c16  = lane & 15;
  const int b    = blockIdx.x;
  const f32x2 Z2 = {0.f, 0.f};

  // ---- phase 0: stage PA + tail + V (small, coalesced)
  if (tid < 128) {
    const int sel = tid >> 5, s = tid & 31;
    *(float4*)&sm[L_PA + sel * 128 + 4 * s] =
        *(const float4*)(PAG + ((size_t)sel * B + b) * 128 + 4 * s);
  } else {
    const int t = tid - 128;
    *(float4*)&sm[L_TAIL + 4 * t] = *(const float4*)(tail + 4 * t);
  }
  if (tid < 200) {
    const int sel = tid / 50, r = tid % 50;
    *(f32x2*)&sm[L_VEC + sel * 100 + 2 * r] =
        *(const f32x2*)(VG + ((size_t)sel * B + b) * KDIM + 2 * r);
  }
  __syncthreads();

  const int net = wv >> 1;
  const int qp  = wv & 1;
  const int vA  = net ? (L_VEC + 0)   : (L_VEC + 200);  // net1: sums, net0: scores
  const int vB  = net ? (L_VEC + 100) : (L_VEC + 300);
  const int pAo = L_PA + net * 256;
  const int pBo = pAo + 128;
  const char* wfb = (const char*)wfrag + net * 21 * 1024;  // global frag base (L2-hot)
  char* h2t0 = smem + H2T_BYTE + (wv * 2 + 0) * 2048;  // [16 rows][128 B], swizzled
  char* h2t1 = smem + H2T_BYTE + (wv * 2 + 1) * 2048;
  char* h3t0 = smem + H3T_BYTE + (wv * 2 + 0) * 1024;  // [16 rows][64 B], swizzled
  char* h3t1 = smem + H3T_BYTE + (wv * 2 + 1) * 1024;
  const float b5v = net ? n2b5[0] : n1b5[0];
  const int t7 = c16 & 7, t3 = c16 & 3;

  // row scalars for both quarters x both chunks
  float sAr[2][2], sBr[2][2];
  #pragma unroll
  for (int qt = 0; qt < 2; ++qt)
    #pragma unroll
    for (int c = 0; c < 2; ++c) {
      const int row = 25 * (2 * qp + qt) + 16 * c + c16;
      const int rr = row < KDIM ? row : (KDIM - 1);   // clamp; pad rows filtered at write
      sAr[qt][c] = sm[vA + rr]; sBr[qt][c] = sm[vB + rr];
    }

  // ---- layer 2: acc2[qt][chunk][mt]; frag/PA/bias loads shared across quarters
  f32x4 acc2[2][2][4];
  #pragma unroll
  for (int qt = 0; qt < 2; ++qt)
    #pragma unroll
    for (int c = 0; c < 2; ++c)
      #pragma unroll
      for (int mt = 0; mt < 4; ++mt) acc2[qt][c][mt] = (f32x4){0.f, 0.f, 0.f, 0.f};

  #pragma unroll
  for (int ks = 0; ks < 4; ++ks) {
    const int jb = 32 * ks + 8 * g;
    const f32x2* pa2 = (const f32x2*)&sm[pAo + jb];
    const f32x2* pb2 = (const f32x2*)&sm[pBo + jb];
    const f32x2* b12 = (const f32x2*)&sm[L_TAIL + net * 128 + jb];
    f32x2 paf[4], pbf[4], b1f[4];
    #pragma unroll
    for (int i = 0; i < 4; ++i) { paf[i] = pa2[i]; pbf[i] = pb2[i]; b1f[i] = b12[i]; }
    bf16x8 hb[2][2];
    #pragma unroll
    for (int qt = 0; qt < 2; ++qt)
      #pragma unroll
      for (int c = 0; c < 2; ++c) {
        const f32x2 sa = {sAr[qt][c], sAr[qt][c]}, sb = {sBr[qt][c], sBr[qt][c]};
        bf16x8 a;
        #pragma unroll
        for (int i2 = 0; i2 < 4; ++i2) {
          f32x2 t = sb * pbf[i2] + b1f[i2];   // v_pk_fma_f32 (contracted)
          t = sa * paf[i2] + t;               // v_pk_fma_f32
          t = vmax2(t, Z2);
          a[2 * i2]     = (__bf16)t[0];       // paired -> v_cvt_pk_bf16_f32
          a[2 * i2 + 1] = (__bf16)t[1];
        }
        hb[qt][c] = a;
      }
    __builtin_amdgcn_s_setprio(1);
    #pragma unroll
    for (int mt = 0; mt < 4; ++mt) {
      const bf16x8 a = *(const bf16x8*)(wfb + (mt * 4 + ks) * 1024 + lane * 16);
      #pragma unroll
      for (int qt = 0; qt < 2; ++qt) {
        acc2[qt][0][mt] = __builtin_amdgcn_mfma_f32_16x16x32_bf16(a, hb[qt][0], acc2[qt][0][mt], 0, 0, 0);
        acc2[qt][1][mt] = __builtin_amdgcn_mfma_f32_16x16x32_bf16(a, hb[qt][1], acc2[qt][1][mt], 0, 0, 0);
      }
    }
    __builtin_amdgcn_s_setprio(0);
  }

  // ---- per-chunk tails: both quarters' chains interleaved (independent)
  #pragma unroll
  for (int c = 0; c < 2; ++c) {
    // h2 epilogues (both quarters)
    #pragma unroll
    for (int qt = 0; qt < 2; ++qt) {
      char* h2t = qt ? h2t1 : h2t0;
      #pragma unroll
      for (int mt = 0; mt < 4; ++mt) {
        const f32x2* b2p = (const f32x2*)&sm[L_TAIL + 256 + net * 64 + 16 * mt + 4 * g];
        const f32x4 x = acc2[qt][c][mt];
        const f32x2 lo = vmax2((f32x2){x[0], x[1]} + b2p[0], Z2);
        const f32x2 hi = vmax2((f32x2){x[2], x[3]} + b2p[1], Z2);
        union { __bf16 e[4]; u32x2 w; } o;
        o.e[0] = (__bf16)lo[0]; o.e[1] = (__bf16)lo[1];
        o.e[2] = (__bf16)hi[0]; o.e[3] = (__bf16)hi[1];
        const int S = (2 * mt + (g >> 1)) ^ t7;
        *(u32x2*)(h2t + c16 * 128 + S * 16 + (g & 1) * 8) = o.w;
      }
    }

    // layer 3 (both quarters)
    f32x4 acc3[2][2];
    #pragma unroll
    for (int qt = 0; qt < 2; ++qt)
      #pragma unroll
      for (int mt = 0; mt < 2; ++mt) acc3[qt][mt] = (f32x4){0.f, 0.f, 0.f, 0.f};
    #pragma unroll
    for (int ks = 0; ks < 2; ++ks) {
      const int S = (4 * ks + g) ^ t7;
      const bf16x8 hbf0 = *(const bf16x8*)(h2t0 + c16 * 128 + S * 16);
      const bf16x8 hbf1 = *(const bf16x8*)(h2t1 + c16 * 128 + S * 16);
      __builtin_amdgcn_s_setprio(1);
      #pragma unroll
      for (int mt = 0; mt < 2; ++mt) {
        const bf16x8 a = *(const bf16x8*)(wfb + (16 + mt * 2 + ks) * 1024 + lane * 16);
        acc3[0][mt] = __builtin_amdgcn_mfma_f32_16x16x32_bf16(a, hbf0, acc3[0][mt], 0, 0, 0);
        acc3[1][mt] = __builtin_amdgcn_mfma_f32_16x16x32_bf16(a, hbf1, acc3[1][mt], 0, 0, 0);
      }
      __builtin_amdgcn_s_setprio(0);
    }
    #pragma unroll
    for (int qt = 0; qt < 2; ++qt) {
      char* h3t = qt ? h3t1 : h3t0;
      #pragma unroll
      for (int mt = 0; mt < 2; ++mt) {
        const f32x2* b3p = (const f32x2*)&sm[L_TAIL + 384 + net * 32 + 16 * mt + 4 * g];
        const f32x4 x = acc3[qt][mt];
        const f32x2 lo = vmax2((f32x2){x[0], x[1]} + b3p[0], Z2);
        const f32x2 hi = vmax2((f32x2){x[2], x[3]} + b3p[1], Z2);
        union { __bf16 e[4]; u32x2 w; } o;
        o.e[0] = (__bf16)lo[0]; o.e[1] = (__bf16)lo[1];
        o.e[2] = (__bf16)hi[0]; o.e[3] = (__bf16)hi[1];
        const int S = (2 * mt + (g >> 1)) ^ t3;
        *(u32x2*)(h3t + c16 * 64 + S * 16 + (g & 1) * 8) = o.w;
      }
    }

    // layer 4 + 5 + per-row reduce (both quarters)
    {
      const int S = g ^ t3;
      const bf16x8 hbf0 = *(const bf16x8*)(h3t0 + c16 * 64 + S * 16);
      const bf16x8 hbf1 = *(const bf16x8*)(h3t1 + c16 * 64 + S * 16);
      const bf16x8 a = *(const bf16x8*)(wfb + 20 * 1024 + lane * 16);
      const f32x4 z = {0.f, 0.f, 0.f, 0.f};
      __builtin_amdgcn_s_setprio(1);
      const f32x4 acc4_0 = __builtin_amdgcn_mfma_f32_16x16x32_bf16(a, hbf0, z, 0, 0, 0);
      const f32x4 acc4_1 = __builtin_amdgcn_mfma_f32_16x16x32_bf16(a, hbf1, z, 0, 0, 0);
      __builtin_amdgcn_s_setprio(0);
      const f32x2* b4p = (const f32x2*)&sm[L_TAIL + 448 + net * 16 + 4 * g];
      const f32x2* w5p = (const f32x2*)&sm[L_TAIL + 480 + net * 16 + 4 * g];
      #pragma unroll
      for (int qt = 0; qt < 2; ++qt) {
        const f32x4 x = qt ? acc4_1 : acc4_0;
        const f32x2 lo = vmax2((f32x2){x[0], x[1]} + b4p[0], Z2);
        const f32x2 hi = vmax2((f32x2){x[2], x[3]} + b4p[1], Z2);
        float v = lo[0] * w5p[0][0] + lo[1] * w5p[0][1]
                + hi[0] * w5p[1][0] + hi[1] * w5p[1][1];   // pad cols: b4=w5=0
        v += __shfl_xor(v, 16); v += __shfl_xor(v, 32);
        const int lr = 16 * c + c16;
        if (g == 0 && lr < 25)
          sm[L_C + net * 128 + 25 * (2 * qp + qt) + lr] = v + b5v;
      }
    }
  }
  __syncthreads();

  // ---- final: sum rows 0..99 of both nets -> sigmoid(mean)
  float v = 0.f;
  if (tid < KDIM) v = sm[L_C + tid] + sm[L_C + 128 + tid];
  if (tid < 128) {
    #pragma unroll
    for (int d = 1; d < 64; d <<= 1) v += __shfl_xor(v, d);
    if ((tid & 63) == 0) sm[tid >> 6] = v;
  }
  __syncthreads();
  if (tid == 0) out[b] = 1.f / (1.f + expf(-0.01f * (sm[0] + sm[1])));
}

extern "C" void kernel_launch(void* const* d_in, const int* in_sizes, int n_in,
                              void* d_out, int out_size, void* d_ws, size_t ws_size,
                              hipStream_t stream) {
  const int*   user_idxs = (const int*)d_in[0];
  const int*   item_idxs = (const int*)d_in[1];
  const int*   uidx_t    = (const int*)d_in[2];
  const int*   iidx_t    = (const int*)d_in[3];
  const float* uscr      = (const float*)d_in[4];
  const float* iscr      = (const float*)d_in[5];
  const float* uemb      = (const float*)d_in[6];
  const float* iemb      = (const float*)d_in[7];

  const int B  = in_sizes[0];
  const int NU = in_sizes[6] / DDIM;
  const int NI = in_sizes[7] / DDIM;

  Weights N1 { (const float*)d_in[8],  (const float*)d_in[9],
               (const float*)d_in[10], (const float*)d_in[11],
               (const float*)d_in[12], (const float*)d_in[13],
               (const float*)d_in[14], (const float*)d_in[15],
               (const float*)d_in[16], (const float*)d_in[17] };
  Weights N2 { (const float*)d_in[18], (const float*)d_in[19],
               (const float*)d_in[20], (const float*)d_in[21],
               (const float*)d_in[22], (const float*)d_in[23],
               (const float*)d_in[24], (const float*)d_in[25],
               (const float*)d_in[26], (const float*)d_in[27] };

  char* ws = (char*)d_ws;
  float* u_rowsum = (float*)ws;
  float* i_rowsum = u_rowsum + NU;
  size_t off = (((size_t)(NU + NI) * 4 + 1023) & ~(size_t)1023);
  __bf16* wfrag = (__bf16*)(ws + off);                   // 42*512 bf16 = 43008 B
  float*  tail  = (float*)(wfrag + (size_t)42 * 512);    // 512 f32 = 2048 B
  __bf16* w1frag = (__bf16*)((char*)tail + 2048);        // 128*512 bf16 = 131072 B
  off += (((size_t)42 * 512 * 2 + 2048 + 131072 + 1023) & ~(size_t)1023);
  float* VG  = (float*)(ws + off);                       // [4][B][100]
  off += (size_t)4 * B * KDIM * 4;
  float* PAG = (float*)(ws + off);                       // [4][B][128]

  float* out = (float*)d_out;

  prep_kernel<<<1024, 256, 0, stream>>>(uemb, iemb, u_rowsum, i_rowsum, NU, NI, N1, N2, wfrag, tail, w1frag);
  const int nbt = (B + 15) / 16;
  proj_kernel<<<nbt * 4, 256, 0, stream>>>(user_idxs, item_idxs, uidx_t, iidx_t,
                                           uscr, iscr, u_rowsum, i_rowsum,
                                           w1frag, VG, PAG, B);
  mlp_kernel<<<B, 256, 0, stream>>>(VG, PAG, tail, N1.b5, N2.b5, wfrag, out, B);
}

// Round 25
// 66.777 us; speedup vs baseline: 1.6729x; 1.0325x over previous
//
#include <hip/hip_runtime.h>
#include <math.h>

#define KDIM 100
#define DDIM 64

typedef __bf16 bf16x8 __attribute__((ext_vector_type(8)));
typedef float  f32x4  __attribute__((ext_vector_type(4)));
typedef float  f32x2  __attribute__((ext_vector_type(2)));
typedef unsigned int u32;
typedef u32 u32x2 __attribute__((ext_vector_type(2)));

struct Weights {
  const float *w1, *b1, *w2, *b2, *w3, *b3, *w4, *b4, *w5, *b5;
};

__device__ __forceinline__ f32x2 vmax2(f32x2 a, f32x2 b) {
#if __has_builtin(__builtin_elementwise_max)
  return __builtin_elementwise_max(a, b);
#else
  return (f32x2){fmaxf(a[0], b[0]), fmaxf(a[1], b[1])};
#endif
}

// ---------------- mlp LDS layout (256 threads, 4 waves, 2 quarters/wave interleaved) ----------------
// floats: L_VEC [4][100] | L_PA [4][128] | L_TAIL [512] | L_C [2][128]
constexpr int L_VEC  = 0;
constexpr int L_PA   = 400;
constexpr int L_TAIL = 912;   // b1[2][128]@0 b2[2][64]@256 b3[2][32]@384 b4[2][16]@448 w5[2][16]@480
constexpr int L_C    = 1424;
constexpr int SM_F   = 1680;                     // 6720 B
constexpr int H2T_BYTE = SM_F * 4;               // 6720; (4 wv x 2 qt) x 16 rows x 128 B
constexpr int H3T_BYTE = H2T_BYTE + 8 * 2048;    // 23104; (4 wv x 2 qt) x 16 rows x 64 B
constexpr int SM_BYTES = H3T_BYTE + 8 * 1024;    // 31296 B

// ---------------- kernel 1: rowsums + frag packing (weights + w1) + bias tail ----------------
// wfrag: [net(2)][frag f(21)][lane(64)][8 bf16]  (layers 2-4, W^T A-frags)
// w1frag: [sel(4)][mt(8)][ks(4)][lane(64)][8 bf16]: elem i = w1sel[(rb+32ks+8g+i)][16mt+c16]
__global__ void prep_kernel(const float* __restrict__ user_emb,
                            const float* __restrict__ item_emb,
                            float* __restrict__ u_rowsum,
                            float* __restrict__ i_rowsum,
                            int NU, int NI, Weights N1, Weights N2,
                            __bf16* __restrict__ wfrag, float* __restrict__ tail,
                            __bf16* __restrict__ w1frag) {
  const int tid  = threadIdx.x;
  const int lane = tid & 63;
  const int g = lane >> 4, c16 = lane & 15;
  const int gw = (blockIdx.x * blockDim.x + tid) >> 6;

  if (gw < 42) {
    const int net = gw / 21, f = gw % 21;
    const Weights W = net ? N2 : N1;
    bf16x8 v;
    if (f < 16) {
      const int mt = f >> 2, ks = f & 3;
      #pragma unroll
      for (int i = 0; i < 8; ++i) {
        const int k = 32 * ks + 8 * g + i, m = 16 * mt + c16;
        v[i] = (__bf16)((k < 100 && m < 50) ? W.w2[k * 50 + m] : 0.f);
      }
    } else if (f < 20) {
      const int mt = (f - 16) >> 1, ks = (f - 16) & 1;
      #pragma unroll
      for (int i = 0; i < 8; ++i) {
        const int k = 32 * ks + 8 * g + i, m = 16 * mt + c16;
        v[i] = (__bf16)((k < 50 && m < 25) ? W.w3[k * 25 + m] : 0.f);
      }
    } else {
      #pragma unroll
      for (int i = 0; i < 8; ++i) {
        const int k = 8 * g + i, m = c16;
        v[i] = (__bf16)((k < 25 && m < 12) ? W.w4[k * 12 + m] : 0.f);
      }
    }
    *(bf16x8*)(wfrag + (size_t)gw * 512 + lane * 8) = v;
  } else if (gw < 170) {
    const int t = gw - 42;            // 0..127 = sel*32 + mt*4 + ks
    const int sel = t >> 5;
    const int f = t & 31;
    const int mt = f >> 2, ks = f & 3;
    const float* w1 = (sel < 2) ? N1.w1 : N2.w1;
    const int rb = (sel & 1) * KDIM;
    bf16x8 v;
    #pragma unroll
    for (int i = 0; i < 8; ++i) {
      const int k = 32 * ks + 8 * g + i, n = 16 * mt + c16;
      v[i] = (__bf16)((k < KDIM && n < KDIM) ? w1[(size_t)(rb + k) * KDIM + n] : 0.f);
    }
    *(bf16x8*)(w1frag + (size_t)t * 512 + lane * 8) = v;
  }

  if (blockIdx.x == 0) {
    for (int e = tid; e < 512; e += 256) {
      float v;
      if (e < 256)      { const int j = e & 127; const Weights W = (e & 128) ? N2 : N1; v = (j < 100) ? W.b1[j] : 0.f; }
      else if (e < 384) { const int t = e - 256; const int j = t & 63; const Weights W = (t & 64) ? N2 : N1; v = (j < 50) ? W.b2[j] : 0.f; }
      else if (e < 448) { const int t = e - 384; const int j = t & 31; const Weights W = (t & 32) ? N2 : N1; v = (j < 25) ? W.b3[j] : 0.f; }
      else if (e < 480) { const int t = e - 448; const int j = t & 15; const Weights W = (t & 16) ? N2 : N1; v = (j < 12) ? W.b4[j] : 0.f; }
      else              { const int t = e - 480; const int j = t & 15; const Weights W = (t & 16) ? N2 : N1; v = (j < 12) ? W.w5[j] : 0.f; }
      tail[e] = v;
    }
  }

  const int NR = NU + NI;
  const int chunk = lane & 15, lrow = lane >> 4;
  const int nwave = (gridDim.x * blockDim.x) >> 6;
  for (int base = gw * 4; base < NR; base += nwave * 4) {
    const int r = base + lrow;
    float s = 0.f;
    if (r < NR) {
      const float* src = (r < NU) ? (user_emb + (size_t)r * DDIM)
                                  : (item_emb + (size_t)(r - NU) * DDIM);
      const float4 v4 = ((const float4*)src)[chunk];
      s = v4.x + v4.y + v4.z + v4.w;
    }
    s += __shfl_xor(s, 1); s += __shfl_xor(s, 2);
    s += __shfl_xor(s, 4); s += __shfl_xor(s, 8);
    if (chunk == 0 && r < NR) {
      if (r < NU) u_rowsum[r] = s; else i_rowsum[r - NU] = s;
    }
  }
}

// ---------------- kernel 2: MFMA layer-1 projections ----------------
// Block = (sel, 16 batches). Gather V[16][<=100] to LDS fp32, then
// PA^T = w1^T @ V^T via 16x16x32 MFMA; D[n=16mt+4g+r][batch=c16] -> f32x4 stores.
__global__ void __launch_bounds__(256) proj_kernel(
    const int* __restrict__ user_idxs, const int* __restrict__ item_idxs,
    const int* __restrict__ uidx_t, const int* __restrict__ iidx_t,
    const float* __restrict__ uscr, const float* __restrict__ iscr,
    const float* __restrict__ u_rowsum, const float* __restrict__ i_rowsum,
    const __bf16* __restrict__ w1frag,
    float* __restrict__ VG, float* __restrict__ PAG, int B)
{
  __shared__ float VT[16][132];   // stride 132 -> 2-way-max bank aliasing on row reads
  const int tid = threadIdx.x;
  const int lane = tid & 63;
  const int wv  = tid >> 6;       // 0..3
  const int g = lane >> 4, c16 = lane & 15;
  const int sel = blockIdx.x & 3;
  const int b0  = (blockIdx.x >> 2) * 16;

  // ---- gather V-tile: 16 threads per batch; idx loads batched ahead of gathers
  {
    const int bl = tid >> 4, strip = tid & 15;
    const int b = b0 + bl;
    const int bb = (b < B) ? b : (B - 1);
    const int sb = (sel & 1) ? item_idxs[bb] : user_idxs[bb];
    const size_t row = (size_t)sb * KDIM;
    if (sel < 2) {
      const int* it = (sel == 0) ? uidx_t : iidx_t;
      const float* rs = (sel == 0) ? u_rowsum : i_rowsum;
      int idxs[8];
      #pragma unroll
      for (int i = 0; i < 8; ++i) {
        const int k = strip + 16 * i;
        idxs[i] = (k < KDIM) ? it[row + k] : 0;
      }
      #pragma unroll
      for (int i = 0; i < 8; ++i) {
        const int k = strip + 16 * i;
        VT[bl][k] = (k < KDIM) ? rs[idxs[i]] : 0.f;
      }
    } else {
      const float* sc = (sel == 2) ? uscr : iscr;
      #pragma unroll
      for (int i = 0; i < 8; ++i) {
        const int k = strip + 16 * i;
        VT[bl][k] = (k < KDIM) ? sc[row + k] : 0.f;
      }
    }
  }
  __syncthreads();

  // ---- VG write-through (fp32 exact, for mlp row scalars)
  {
    const int bl = tid >> 4, strip = tid & 15;
    const int b = b0 + bl;
    if (b < B) {
      float* dst = VG + ((size_t)sel * B + b) * KDIM;
      #pragma unroll
      for (int i = 0; i < 7; ++i) {
        const int k = strip + 16 * i;
        if (k < KDIM) dst[k] = VT[bl][k];
      }
    }
  }

  // ---- B-frags (V): b[i] = V[batch c16][32ks+8g+i]
  bf16x8 bf[4];
  #pragma unroll
  for (int ks = 0; ks < 4; ++ks) {
    const float* src = &VT[c16][32 * ks + 8 * g];
    bf16x8 a;
    #pragma unroll
    for (int i = 0; i < 8; ++i) a[i] = (__bf16)src[i];
    bf[ks] = a;
  }

  // ---- MFMA: wave wv handles n-tiles mt = 2wv, 2wv+1
  f32x4 acc[2];
  #pragma unroll
  for (int m2 = 0; m2 < 2; ++m2) acc[m2] = (f32x4){0.f, 0.f, 0.f, 0.f};
  #pragma unroll
  for (int m2 = 0; m2 < 2; ++m2) {
    const int mt = 2 * wv + m2;
    #pragma unroll
    for (int ks = 0; ks < 4; ++ks) {
      const bf16x8 a = *(const bf16x8*)(w1frag + ((size_t)(sel * 32 + mt * 4 + ks)) * 512 + lane * 8);
      acc[m2] = __builtin_amdgcn_mfma_f32_16x16x32_bf16(a, bf[ks], acc[m2], 0, 0, 0);
    }
  }

  // ---- store PA
  {
    const int b = b0 + c16;
    if (b < B) {
      #pragma unroll
      for (int m2 = 0; m2 < 2; ++m2) {
        const int mt = 2 * wv + m2;
        *(f32x4*)(PAG + ((size_t)sel * B + b) * 128 + 16 * mt + 4 * g) = acc[m2];
      }
    }
  }
}

// ---------------- kernel 3: quarter-interleaved swapped-operand MFMA chain ----------------
// 256 threads = 4 waves; wave wv: net = wv>>1, qp = wv&1 -> quarters {2qp, 2qp+1}
// processed CONCURRENTLY; frag/PA/bias loads shared across the two quarters.
// setprio removed (issue-slot tax at ~88% issue saturation; T5 regime check).
__global__ void __launch_bounds__(256, 3) mlp_kernel(
    const float* __restrict__ VG, const float* __restrict__ PAG,
    const float* __restrict__ tail,
    const float* __restrict__ n1b5, const float* __restrict__ n2b5,
    const __bf16* __restrict__ wfrag, float* __restrict__ out, int B)
{
  __shared__ __align__(16) char smem[SM_BYTES];
  float* sm = (float*)smem;
  const int tid  = threadIdx.x;
  const int lane = tid & 63;
  const int wv   = tid >> 6;     // 0..3
  const int g    = lane >> 4;
  const int c16  = lane & 15;
  const int b    = blockIdx.x;
  const f32x2 Z2 = {0.f, 0.f};

  // ---- phase 0: stage PA + tail + V (small, coalesced)
  if (tid < 128) {
    const int sel = tid >> 5, s = tid & 31;
    *(float4*)&sm[L_PA + sel * 128 + 4 * s] =
        *(const float4*)(PAG + ((size_t)sel * B + b) * 128 + 4 * s);
  } else {
    const int t = tid - 128;
    *(float4*)&sm[L_TAIL + 4 * t] = *(const float4*)(tail + 4 * t);
  }
  if (tid < 200) {
    const int sel = tid / 50, r = tid % 50;
    *(f32x2*)&sm[L_VEC + sel * 100 + 2 * r] =
        *(const f32x2*)(VG + ((size_t)sel * B + b) * KDIM + 2 * r);
  }
  __syncthreads();

  const int net = wv >> 1;
  const int qp  = wv & 1;
  const int vA  = net ? (L_VEC + 0)   : (L_VEC + 200);  // net1: sums, net0: scores
  const int vB  = net ? (L_VEC + 100) : (L_VEC + 300);
  const int pAo = L_PA + net * 256;
  const int pBo = pAo + 128;
  const char* wfb = (const char*)wfrag + net * 21 * 1024;  // global frag base (L2-hot)
  char* h2t0 = smem + H2T_BYTE + (wv * 2 + 0) * 2048;  // [16 rows][128 B], swizzled
  char* h2t1 = smem + H2T_BYTE + (wv * 2 + 1) * 2048;
  char* h3t0 = smem + H3T_BYTE + (wv * 2 + 0) * 1024;  // [16 rows][64 B], swizzled
  char* h3t1 = smem + H3T_BYTE + (wv * 2 + 1) * 1024;
  const float b5v = net ? n2b5[0] : n1b5[0];
  const int t7 = c16 & 7, t3 = c16 & 3;

  float sAr[2][2], sBr[2][2];
  #pragma unroll
  for (int qt = 0; qt < 2; ++qt)
    #pragma unroll
    for (int c = 0; c < 2; ++c) {
      const int row = 25 * (2 * qp + qt) + 16 * c + c16;
      const int rr = row < KDIM ? row : (KDIM - 1);   // clamp; pad rows filtered at write
      sAr[qt][c] = sm[vA + rr]; sBr[qt][c] = sm[vB + rr];
    }

  // ---- layer 2: acc2[qt][chunk][mt]
  f32x4 acc2[2][2][4];
  #pragma unroll
  for (int qt = 0; qt < 2; ++qt)
    #pragma unroll
    for (int c = 0; c < 2; ++c)
      #pragma unroll
      for (int mt = 0; mt < 4; ++mt) acc2[qt][c][mt] = (f32x4){0.f, 0.f, 0.f, 0.f};

  #pragma unroll
  for (int ks = 0; ks < 4; ++ks) {
    const int jb = 32 * ks + 8 * g;
    const f32x2* pa2 = (const f32x2*)&sm[pAo + jb];
    const f32x2* pb2 = (const f32x2*)&sm[pBo + jb];
    const f32x2* b12 = (const f32x2*)&sm[L_TAIL + net * 128 + jb];
    f32x2 paf[4], pbf[4], b1f[4];
    #pragma unroll
    for (int i = 0; i < 4; ++i) { paf[i] = pa2[i]; pbf[i] = pb2[i]; b1f[i] = b12[i]; }
    bf16x8 hb[2][2];
    #pragma unroll
    for (int qt = 0; qt < 2; ++qt)
      #pragma unroll
      for (int c = 0; c < 2; ++c) {
        const f32x2 sa = {sAr[qt][c], sAr[qt][c]}, sb = {sBr[qt][c], sBr[qt][c]};
        bf16x8 a;
        #pragma unroll
        for (int i2 = 0; i2 < 4; ++i2) {
          f32x2 t = sb * pbf[i2] + b1f[i2];   // v_pk_fma_f32 (contracted)
          t = sa * paf[i2] + t;               // v_pk_fma_f32
          t = vmax2(t, Z2);
          a[2 * i2]     = (__bf16)t[0];       // paired -> v_cvt_pk_bf16_f32
          a[2 * i2 + 1] = (__bf16)t[1];
        }
        hb[qt][c] = a;
      }
    #pragma unroll
    for (int mt = 0; mt < 4; ++mt) {
      const bf16x8 a = *(const bf16x8*)(wfb + (mt * 4 + ks) * 1024 + lane * 16);
      #pragma unroll
      for (int qt = 0; qt < 2; ++qt) {
        acc2[qt][0][mt] = __builtin_amdgcn_mfma_f32_16x16x32_bf16(a, hb[qt][0], acc2[qt][0][mt], 0, 0, 0);
        acc2[qt][1][mt] = __builtin_amdgcn_mfma_f32_16x16x32_bf16(a, hb[qt][1], acc2[qt][1][mt], 0, 0, 0);
      }
    }
  }

  // ---- per-chunk tails: both quarters' chains interleaved (independent)
  #pragma unroll
  for (int c = 0; c < 2; ++c) {
    #pragma unroll
    for (int qt = 0; qt < 2; ++qt) {
      char* h2t = qt ? h2t1 : h2t0;
      #pragma unroll
      for (int mt = 0; mt < 4; ++mt) {
        const f32x2* b2p = (const f32x2*)&sm[L_TAIL + 256 + net * 64 + 16 * mt + 4 * g];
        const f32x4 x = acc2[qt][c][mt];
        const f32x2 lo = vmax2((f32x2){x[0], x[1]} + b2p[0], Z2);
        const f32x2 hi = vmax2((f32x2){x[2], x[3]} + b2p[1], Z2);
        union { __bf16 e[4]; u32x2 w; } o;
        o.e[0] = (__bf16)lo[0]; o.e[1] = (__bf16)lo[1];
        o.e[2] = (__bf16)hi[0]; o.e[3] = (__bf16)hi[1];
        const int S = (2 * mt + (g >> 1)) ^ t7;
        *(u32x2*)(h2t + c16 * 128 + S * 16 + (g & 1) * 8) = o.w;
      }
    }

    f32x4 acc3[2][2];
    #pragma unroll
    for (int qt = 0; qt < 2; ++qt)
      #pragma unroll
      for (int mt = 0; mt < 2; ++mt) acc3[qt][mt] = (f32x4){0.f, 0.f, 0.f, 0.f};
    #pragma unroll
    for (int ks = 0; ks < 2; ++ks) {
      const int S = (4 * ks + g) ^ t7;
      const bf16x8 hbf0 = *(const bf16x8*)(h2t0 + c16 * 128 + S * 16);
      const bf16x8 hbf1 = *(const bf16x8*)(h2t1 + c16 * 128 + S * 16);
      #pragma unroll
      for (int mt = 0; mt < 2; ++mt) {
        const bf16x8 a = *(const bf16x8*)(wfb + (16 + mt * 2 + ks) * 1024 + lane * 16);
        acc3[0][mt] = __builtin_amdgcn_mfma_f32_16x16x32_bf16(a, hbf0, acc3[0][mt], 0, 0, 0);
        acc3[1][mt] = __builtin_amdgcn_mfma_f32_16x16x32_bf16(a, hbf1, acc3[1][mt], 0, 0, 0);
      }
    }
    #pragma unroll
    for (int qt = 0; qt < 2; ++qt) {
      char* h3t = qt ? h3t1 : h3t0;
      #pragma unroll
      for (int mt = 0; mt < 2; ++mt) {
        const f32x2* b3p = (const f32x2*)&sm[L_TAIL + 384 + net * 32 + 16 * mt + 4 * g];
        const f32x4 x = acc3[qt][mt];
        const f32x2 lo = vmax2((f32x2){x[0], x[1]} + b3p[0], Z2);
        const f32x2 hi = vmax2((f32x2){x[2], x[3]} + b3p[1], Z2);
        union { __bf16 e[4]; u32x2 w; } o;
        o.e[0] = (__bf16)lo[0]; o.e[1] = (__bf16)lo[1];
        o.e[2] = (__bf16)hi[0]; o.e[3] = (__bf16)hi[1];
        const int S = (2 * mt + (g >> 1)) ^ t3;
        *(u32x2*)(h3t + c16 * 64 + S * 16 + (g & 1) * 8) = o.w;
      }
    }

    {
      const int S = g ^ t3;
      const bf16x8 hbf0 = *(const bf16x8*)(h3t0 + c16 * 64 + S * 16);
      const bf16x8 hbf1 = *(const bf16x8*)(h3t1 + c16 * 64 + S * 16);
      const bf16x8 a = *(const bf16x8*)(wfb + 20 * 1024 + lane * 16);
      const f32x4 z = {0.f, 0.f, 0.f, 0.f};
      const f32x4 acc4_0 = __builtin_amdgcn_mfma_f32_16x16x32_bf16(a, hbf0, z, 0, 0, 0);
      const f32x4 acc4_1 = __builtin_amdgcn_mfma_f32_16x16x32_bf16(a, hbf1, z, 0, 0, 0);
      const f32x2* b4p = (const f32x2*)&sm[L_TAIL + 448 + net * 16 + 4 * g];
      const f32x2* w5p = (const f32x2*)&sm[L_TAIL + 480 + net * 16 + 4 * g];
      #pragma unroll
      for (int qt = 0; qt < 2; ++qt) {
        const f32x4 x = qt ? acc4_1 : acc4_0;
        const f32x2 lo = vmax2((f32x2){x[0], x[1]} + b4p[0], Z2);
        const f32x2 hi = vmax2((f32x2){x[2], x[3]} + b4p[1], Z2);
        float v = lo[0] * w5p[0][0] + lo[1] * w5p[0][1]
                + hi[0] * w5p[1][0] + hi[1] * w5p[1][1];   // pad cols: b4=w5=0
        v += __shfl_xor(v, 16); v += __shfl_xor(v, 32);
        const int lr = 16 * c + c16;
        if (g == 0 && lr < 25)
          sm[L_C + net * 128 + 25 * (2 * qp + qt) + lr] = v + b5v;
      }
    }
  }
  __syncthreads();

  // ---- final: sum rows 0..99 of both nets -> sigmoid(mean)
  float v = 0.f;
  if (tid < KDIM) v = sm[L_C + tid] + sm[L_C + 128 + tid];
  if (tid < 128) {
    #pragma unroll
    for (int d = 1; d < 64; d <<= 1) v += __shfl_xor(v, d);
    if ((tid & 63) == 0) sm[tid >> 6] = v;
  }
  __syncthreads();
  if (tid == 0) out[b] = 1.f / (1.f + expf(-0.01f * (sm[0] + sm[1])));
}

extern "C" void kernel_launch(void* const* d_in, const int* in_sizes, int n_in,
                              void* d_out, int out_size, void* d_ws, size_t ws_size,
                              hipStream_t stream) {
  const int*   user_idxs = (const int*)d_in[0];
  const int*   item_idxs = (const int*)d_in[1];
  const int*   uidx_t    = (const int*)d_in[2];
  const int*   iidx_t    = (const int*)d_in[3];
  const float* uscr      = (const float*)d_in[4];
  const float* iscr      = (const float*)d_in[5];
  const float* uemb      = (const float*)d_in[6];
  const float* iemb      = (const float*)d_in[7];

  const int B  = in_sizes[0];
  const int NU = in_sizes[6] / DDIM;
  const int NI = in_sizes[7] / DDIM;

  Weights N1 { (const float*)d_in[8],  (const float*)d_in[9],
               (const float*)d_in[10], (const float*)d_in[11],
               (const float*)d_in[12], (const float*)d_in[13],
               (const float*)d_in[14], (const float*)d_in[15],
               (const float*)d_in[16], (const float*)d_in[17] };
  Weights N2 { (const float*)d_in[18], (const float*)d_in[19],
               (const float*)d_in[20], (const float*)d_in[21],
               (const float*)d_in[22], (const float*)d_in[23],
               (const float*)d_in[24], (const float*)d_in[25],
               (const float*)d_in[26], (const float*)d_in[27] };

  char* ws = (char*)d_ws;
  float* u_rowsum = (float*)ws;
  float* i_rowsum = u_rowsum + NU;
  size_t off = (((size_t)(NU + NI) * 4 + 1023) & ~(size_t)1023);
  __bf16* wfrag = (__bf16*)(ws + off);                   // 42*512 bf16 = 43008 B
  float*  tail  = (float*)(wfrag + (size_t)42 * 512);    // 512 f32 = 2048 B
  __bf16* w1frag = (__bf16*)((char*)tail + 2048);        // 128*512 bf16 = 131072 B
  off += (((size_t)42 * 512 * 2 + 2048 + 131072 + 1023) & ~(size_t)1023);
  float* VG  = (float*)(ws + off);                       // [4][B][100]
  off += (size_t)4 * B * KDIM * 4;
  float* PAG = (float*)(ws + off);                       // [4][B][128]

  float* out = (float*)d_out;

  prep_kernel<<<2048, 256, 0, stream>>>(uemb, iemb, u_rowsum, i_rowsum, NU, NI, N1, N2, wfrag, tail, w1frag);
  const int nbt = (B + 15) / 16;
  proj_kernel<<<nbt * 4, 256, 0, stream>>>(user_idxs, item_idxs, uidx_t, iidx_t,
                                           uscr, iscr, u_rowsum, i_rowsum,
                                           w1frag, VG, PAG, B);
  mlp_kernel<<<B, 256, 0, stream>>>(VG, PAG, tail, N1.b5, N2.b5, wfrag, out, B);
}